// Round 1
// baseline (28219.980 us; speedup 1.0000x reference)
//
#include <hip/hip_runtime.h>
#include <cmath>

#define NLAYERS 12
#define NHEADS  12
#define DM      768
#define VOCAB   50257
#define TSEQ    1024
#define BT      4096   // B*T = 4*1024

// ---------------- embedding ----------------
__global__ void embed_kernel(const int* __restrict__ inp, const float* __restrict__ wte,
                             const float* __restrict__ wpe, float* __restrict__ x) {
    int idx = blockIdx.x * 256 + threadIdx.x;          // over BT*DM = 3145728
    int m = idx / DM, c = idx % DM;
    int tok = inp[m];
    int t = m & (TSEQ - 1);
    x[idx] = wte[(size_t)tok * DM + c] + wpe[t * DM + c];
}

// ---------------- layernorm ----------------
__global__ void ln_kernel(const float* __restrict__ x, const float* __restrict__ w,
                          const float* __restrict__ b, float* __restrict__ y) {
    int row = blockIdx.x, tid = threadIdx.x;
    const float* xr = x + (size_t)row * DM;
    float s = 0.f, q = 0.f;
    for (int c = tid; c < DM; c += 256) { float v = xr[c]; s += v; q += v * v; }
    __shared__ float rs[256], rq[256];
    rs[tid] = s; rq[tid] = q; __syncthreads();
    for (int o = 128; o; o >>= 1) {
        if (tid < o) { rs[tid] += rs[tid + o]; rq[tid] += rq[tid + o]; }
        __syncthreads();
    }
    float mu  = rs[0] * (1.0f / DM);
    float var = rq[0] * (1.0f / DM) - mu * mu;
    float inv = rsqrtf(var + 1e-5f);
    for (int c = tid; c < DM; c += 256)
        y[(size_t)row * DM + c] = (xr[c] - mu) * inv * w[c] + b[c];
}

// ---------------- gelu ----------------
__device__ __forceinline__ float gelu_tanh(float v) {
    float u = 0.7978845608028654f * (v + 0.044715f * v * v * v);
    return 0.5f * v * (1.0f + tanhf(u));
}

// ---------------- GEMM NN: C[M,N] = A[M,K] @ W[K,N] + bias (+gelu) (+resid) ----------------
// 64x64 tile, BK=16, 256 threads, 4x4 per thread. All dims here are multiples of tile.
__global__ void gemm_nn_kernel(const float* __restrict__ A, const float* __restrict__ W,
                               const float* __restrict__ bias, const float* __restrict__ resid,
                               float* __restrict__ C, int M, int N, int K, int dogelu) {
    __shared__ float As[16][68];   // +4 pad keeps 16B alignment, breaks bank conflicts
    __shared__ float Bs[16][68];
    int bm = blockIdx.y * 64, bn = blockIdx.x * 64;
    int tid = threadIdx.x;
    int tx = tid & 15, ty = tid >> 4;
    float acc[4][4] = {};
    for (int k0 = 0; k0 < K; k0 += 16) {
#pragma unroll
        for (int i = 0; i < 4; ++i) {
            int e = tid + i * 256;
            int am = e >> 4, ak = e & 15;
            As[ak][am] = A[(size_t)(bm + am) * K + k0 + ak];
            int bk = e >> 6, bn2 = e & 63;
            Bs[bk][bn2] = W[(size_t)(k0 + bk) * N + bn + bn2];
        }
        __syncthreads();
#pragma unroll
        for (int kk = 0; kk < 16; ++kk) {
            float4 av4 = *reinterpret_cast<const float4*>(&As[kk][ty * 4]);
            float4 bv4 = *reinterpret_cast<const float4*>(&Bs[kk][tx * 4]);
            float av[4] = {av4.x, av4.y, av4.z, av4.w};
            float bv[4] = {bv4.x, bv4.y, bv4.z, bv4.w};
#pragma unroll
            for (int i = 0; i < 4; ++i)
#pragma unroll
                for (int j = 0; j < 4; ++j) acc[i][j] += av[i] * bv[j];
        }
        __syncthreads();
    }
#pragma unroll
    for (int i = 0; i < 4; ++i) {
        int row = bm + ty * 4 + i;
#pragma unroll
        for (int j = 0; j < 4; ++j) {
            int col = bn + tx * 4 + j;
            float v = acc[i][j] + bias[col];
            if (dogelu) v = gelu_tanh(v);
            if (resid) v += resid[(size_t)row * N + col];
            C[(size_t)row * N + col] = v;
        }
    }
}

// ---------------- GEMM NT: C[M,N] = A[M,K] @ B[N,K]^T  (lm_head, N not tile-aligned) ----------------
__global__ void gemm_nt_kernel(const float* __restrict__ A, const float* __restrict__ B,
                               float* __restrict__ C, int M, int N, int K) {
    __shared__ float As[16][68];
    __shared__ float Bs[16][68];
    int bm = blockIdx.y * 64, bn = blockIdx.x * 64;
    int tid = threadIdx.x;
    int tx = tid & 15, ty = tid >> 4;
    float acc[4][4] = {};
    for (int k0 = 0; k0 < K; k0 += 16) {
#pragma unroll
        for (int i = 0; i < 4; ++i) {
            int e = tid + i * 256;
            int am = e >> 4, ak = e & 15;
            As[ak][am] = A[(size_t)(bm + am) * K + k0 + ak];
            Bs[ak][am] = (bn + am < N) ? B[(size_t)(bn + am) * K + k0 + ak] : 0.0f;
        }
        __syncthreads();
#pragma unroll
        for (int kk = 0; kk < 16; ++kk) {
            float4 av4 = *reinterpret_cast<const float4*>(&As[kk][ty * 4]);
            float4 bv4 = *reinterpret_cast<const float4*>(&Bs[kk][tx * 4]);
            float av[4] = {av4.x, av4.y, av4.z, av4.w};
            float bv[4] = {bv4.x, bv4.y, bv4.z, bv4.w};
#pragma unroll
            for (int i = 0; i < 4; ++i)
#pragma unroll
                for (int j = 0; j < 4; ++j) acc[i][j] += av[i] * bv[j];
        }
        __syncthreads();
    }
#pragma unroll
    for (int i = 0; i < 4; ++i) {
        int row = bm + ty * 4 + i;
#pragma unroll
        for (int j = 0; j < 4; ++j) {
            int col = bn + tx * 4 + j;
            if (col < N) C[(size_t)row * N + col] = acc[i][j];
        }
    }
}

// ---------------- causal attention: one block (64 threads) per (b,h,q) ----------------
// qkv layout: [BT, 3*DM]; q at col h*64, k at 768+h*64, v at 1536+h*64
__global__ void attn_kernel(const float* __restrict__ qkv, float* __restrict__ ctx) {
    int blk = blockIdx.x;                 // b*NHEADS*TSEQ + h*TSEQ + q
    int q = blk & (TSEQ - 1);
    int h = (blk >> 10) % NHEADS;
    int b = blk / (NHEADS * TSEQ);
    int tid = threadIdx.x;                // 0..63, one wave

    __shared__ float s[TSEQ];
    __shared__ float qs[64];

    const float* qp = qkv + ((size_t)(b * TSEQ + q)) * (3 * DM) + h * 64;
    qs[tid] = qp[tid];
    __syncthreads();

    float lmax = -INFINITY;
    for (int kk = tid; kk <= q; kk += 64) {
        const float* kp = qkv + ((size_t)(b * TSEQ + kk)) * (3 * DM) + DM + h * 64;
        float acc = 0.f;
#pragma unroll 8
        for (int d = 0; d < 64; ++d) acc += qs[d] * kp[d];
        acc *= 0.125f;                    // 1/sqrt(64)
        s[kk] = acc;
        lmax = fmaxf(lmax, acc);
    }
    for (int o = 32; o; o >>= 1) lmax = fmaxf(lmax, __shfl_xor(lmax, o));

    float lsum = 0.f;
    for (int kk = tid; kk <= q; kk += 64) {
        float p = __expf(s[kk] - lmax);
        s[kk] = p;
        lsum += p;
    }
    for (int o = 32; o; o >>= 1) lsum += __shfl_xor(lsum, o);
    __syncthreads();

    float invsum = 1.0f / lsum;
    float acc = 0.f;
    int d = tid;
    for (int kk = 0; kk <= q; ++kk) {
        const float* vp = qkv + ((size_t)(b * TSEQ + kk)) * (3 * DM) + 2 * DM + h * 64;
        acc += s[kk] * vp[d];
    }
    ctx[((size_t)(b * TSEQ + q)) * DM + h * 64 + d] = acc * invsum;
}

// ---------------- loss ----------------
__global__ void loss1_kernel(const float* __restrict__ logits, const int* __restrict__ target,
                             float* __restrict__ nll) {
    int row = blockIdx.x, tid = threadIdx.x;
    const float* lr = logits + (size_t)row * VOCAB;
    float m = -INFINITY, ssum = 0.f;
    for (int v = tid; v < VOCAB; v += 256) {
        float l = lr[v];
        if (l > m) { ssum = ssum * __expf(m - l) + 1.0f; m = l; }
        else       { ssum += __expf(l - m); }
    }
    __shared__ float sm[256], ss[256];
    sm[tid] = m; ss[tid] = ssum; __syncthreads();
    for (int o = 128; o; o >>= 1) {
        if (tid < o) {
            float m2 = sm[tid + o], s2 = ss[tid + o];
            float mm = fmaxf(sm[tid], m2);
            ss[tid] = ss[tid] * __expf(sm[tid] - mm) + s2 * __expf(m2 - mm);
            sm[tid] = mm;
        }
        __syncthreads();
    }
    if (tid == 0) {
        float lse = sm[0] + logf(ss[0]);
        nll[row] = lse - lr[target[row]];
    }
}

__global__ void loss2_kernel(const float* __restrict__ nll, float* __restrict__ loss) {
    int tid = threadIdx.x;
    float s = 0.f;
    for (int i = tid; i < BT; i += 1024) s += nll[i];
    __shared__ float r[1024];
    r[tid] = s; __syncthreads();
    for (int o = 512; o; o >>= 1) { if (tid < o) r[tid] += r[tid + o]; __syncthreads(); }
    if (tid == 0) *loss = r[0] * (1.0f / BT);
}

// ---------------- launcher ----------------
extern "C" void kernel_launch(void* const* d_in, const int* in_sizes, int n_in,
                              void* d_out, int out_size, void* d_ws, size_t ws_size,
                              hipStream_t stream) {
    const int*   inp    = (const int*)  d_in[0];
    const int*   target = (const int*)  d_in[1];
    const float* wte    = (const float*)d_in[2];
    const float* wpe    = (const float*)d_in[3];
    const float* ln1_w  = (const float*)d_in[4];
    const float* ln1_b  = (const float*)d_in[5];
    const float* attn_w = (const float*)d_in[6];
    const float* attn_b = (const float*)d_in[7];
    const float* proj_w = (const float*)d_in[8];
    const float* proj_b = (const float*)d_in[9];
    const float* ln2_w  = (const float*)d_in[10];
    const float* ln2_b  = (const float*)d_in[11];
    const float* fc_w   = (const float*)d_in[12];
    const float* fc_b   = (const float*)d_in[13];
    const float* fc2_w  = (const float*)d_in[14];
    const float* fc2_b  = (const float*)d_in[15];
    const float* lnf_w  = (const float*)d_in[16];
    const float* lnf_b  = (const float*)d_in[17];
    float* out = (float*)d_out;

    float* ws   = (float*)d_ws;
    float* x    = ws;                              // [BT, DM]
    float* tmp  = x    + (size_t)BT * DM;          // [BT, DM]
    float* ctxb = tmp  + (size_t)BT * DM;          // [BT, DM]
    float* big  = ctxb + (size_t)BT * DM;          // [BT, 4*DM] (union: qkv uses [BT,3*DM])
    float* nll  = big  + (size_t)BT * 4 * DM;      // [BT]

    embed_kernel<<<BT * DM / 256, 256, 0, stream>>>(inp, wte, wpe, x);

    for (int i = 0; i < NLAYERS; ++i) {
        ln_kernel<<<BT, 256, 0, stream>>>(x, ln1_w + i * DM, ln1_b + i * DM, tmp);
        gemm_nn_kernel<<<dim3(3 * DM / 64, BT / 64), 256, 0, stream>>>(
            tmp, attn_w + (size_t)i * DM * 3 * DM, attn_b + i * 3 * DM, nullptr,
            big, BT, 3 * DM, DM, 0);
        attn_kernel<<<4 * NHEADS * TSEQ, 64, 0, stream>>>(big, ctxb);
        gemm_nn_kernel<<<dim3(DM / 64, BT / 64), 256, 0, stream>>>(
            ctxb, proj_w + (size_t)i * DM * DM, proj_b + i * DM, x,
            x, BT, DM, DM, 0);
        ln_kernel<<<BT, 256, 0, stream>>>(x, ln2_w + i * DM, ln2_b + i * DM, tmp);
        gemm_nn_kernel<<<dim3(4 * DM / 64, BT / 64), 256, 0, stream>>>(
            tmp, fc_w + (size_t)i * DM * 4 * DM, fc_b + i * 4 * DM, nullptr,
            big, BT, 4 * DM, DM, 1);
        gemm_nn_kernel<<<dim3(DM / 64, BT / 64), 256, 0, stream>>>(
            big, fc2_w + (size_t)i * 4 * DM * DM, fc2_b + i * DM, x,
            x, BT, DM, 4 * DM, 0);
    }

    ln_kernel<<<BT, 256, 0, stream>>>(x, lnf_w, lnf_b, tmp);
    gemm_nt_kernel<<<dim3((VOCAB + 63) / 64, BT / 64), 256, 0, stream>>>(
        tmp, wte, out, BT, VOCAB, DM);
    loss1_kernel<<<BT, 256, 0, stream>>>(out, target, nll);
    loss2_kernel<<<1, 1024, 0, stream>>>(nll, out + (size_t)out_size - 1);
}

// Round 2
// 17292.569 us; speedup vs baseline: 1.6319x; 1.6319x over previous
//
#include <hip/hip_runtime.h>
#include <hip/hip_bf16.h>
#include <cmath>

#define NLAYERS 12
#define NHEADS  12
#define DM      768
#define VOCAB   50257
#define TSEQ    1024
#define BT      4096   // B*T

typedef __attribute__((ext_vector_type(4))) float f32x4;
typedef __attribute__((ext_vector_type(8))) short bf16x8;

typedef __hip_bfloat16 bf16;

// ---------------- helpers ----------------
__device__ __forceinline__ void gload16(const void* g, void* l) {
    __builtin_amdgcn_global_load_lds(
        (const __attribute__((address_space(1))) void*)g,
        (__attribute__((address_space(3))) void*)l, 16, 0, 0);
}

__device__ __forceinline__ float gelu_tanh(float v) {
    float u = 0.7978845608028654f * (v + 0.044715f * v * v * v);
    return 0.5f * v * (1.0f + tanhf(u));
}

// ---------------- weight prep ----------------
// fp32 [L][K][N] -> bf16 [L][N][K] (transpose per layer)
__global__ void transpose_bf16_kernel(const float* __restrict__ in, bf16* __restrict__ out,
                                      int K, int N) {
    __shared__ float tile[32][33];
    size_t lofs = (size_t)blockIdx.z * K * N;
    int k0 = blockIdx.y * 32, n0 = blockIdx.x * 32;
    int tx = threadIdx.x, ty = threadIdx.y;      // 32x8
#pragma unroll
    for (int i = 0; i < 32; i += 8)
        tile[ty + i][tx] = in[lofs + (size_t)(k0 + ty + i) * N + n0 + tx];
    __syncthreads();
#pragma unroll
    for (int i = 0; i < 32; i += 8)
        out[lofs + (size_t)(n0 + ty + i) * K + k0 + tx] = (bf16)tile[tx][ty + i];
}

__global__ void tobf16_kernel(const float* __restrict__ in, bf16* __restrict__ out, size_t n) {
    size_t i = (size_t)blockIdx.x * 256 + threadIdx.x;
    if (i < n) out[i] = (bf16)in[i];
}

// ---------------- embedding (fp32 residual stream) ----------------
__global__ void embed_kernel(const int* __restrict__ inp, const float* __restrict__ wte,
                             const float* __restrict__ wpe, float* __restrict__ x) {
    int idx = blockIdx.x * 256 + threadIdx.x;
    int m = idx / DM, c = idx % DM;
    int tok = inp[m];
    int t = m & (TSEQ - 1);
    x[idx] = wte[(size_t)tok * DM + c] + wpe[t * DM + c];
}

// ---------------- layernorm: fp32 in -> bf16 out ----------------
__global__ void ln_kernel(const float* __restrict__ x, const float* __restrict__ w,
                          const float* __restrict__ b, bf16* __restrict__ y) {
    int row = blockIdx.x, tid = threadIdx.x;
    const float* xr = x + (size_t)row * DM;
    float s = 0.f, q = 0.f;
    for (int c = tid; c < DM; c += 256) { float v = xr[c]; s += v; q += v * v; }
    __shared__ float rs[256], rq[256];
    rs[tid] = s; rq[tid] = q; __syncthreads();
    for (int o = 128; o; o >>= 1) {
        if (tid < o) { rs[tid] += rs[tid + o]; rq[tid] += rq[tid + o]; }
        __syncthreads();
    }
    float mu  = rs[0] * (1.0f / DM);
    float var = rq[0] * (1.0f / DM) - mu * mu;
    float inv = rsqrtf(var + 1e-5f);
    for (int c = tid; c < DM; c += 256)
        y[(size_t)row * DM + c] = (bf16)((xr[c] - mu) * inv * w[c] + b[c]);
}

// ---------------- bf16 MFMA GEMM ----------------
// C[M,N] = A[M,K] @ Bt[N,K]^T, fp32 accum. 128x128 tile, BK=32, 4 waves.
// flags: 1 = gelu, 2 = bf16 output, 4 = clamp N (lm_head tail)
#define GF_GELU  1
#define GF_OBF16 2
#define GF_CLAMP 4
__global__ __launch_bounds__(256) void gemm_bf16_kernel(
    const bf16* __restrict__ A, const bf16* __restrict__ Bt,
    const float* __restrict__ bias, const float* __restrict__ resid,
    void* __restrict__ C, int M, int N, int K, int flags) {
    __shared__ short ldsA[128 * 32];
    __shared__ short ldsB[128 * 32];
    int tid = threadIdx.x;
    int lane = tid & 63, w = tid >> 6;
    int wm = w >> 1, wn = w & 1;
    int bm = blockIdx.y * 128, bn = blockIdx.x * 128;
    int r = lane & 15, kq = lane >> 4;

    f32x4 acc[4][4] = {};

    for (int k0 = 0; k0 < K; k0 += 32) {
        // stage A tile [128][32] and B tile [128][32] (both row-major in k)
#pragma unroll
        for (int i = 0; i < 2; ++i) {
            int chunk = i * 256 + tid;           // 16B chunk id
            int row = chunk >> 2, kqq = chunk & 3;
            const bf16* ga = A + (size_t)(bm + row) * K + k0 + kqq * 8;
            gload16(ga, ldsA + (size_t)(i * 256 + w * 64) * 8);
            int brow = bn + row;
            if (flags & GF_CLAMP) brow = min(brow, N - 1);
            const bf16* gb = Bt + (size_t)brow * K + k0 + kqq * 8;
            gload16(gb, ldsB + (size_t)(i * 256 + w * 64) * 8);
        }
        __syncthreads();

        bf16x8 af[4], bf[4];
#pragma unroll
        for (int m = 0; m < 4; ++m)
            af[m] = *reinterpret_cast<bf16x8*>(&ldsA[(wm * 64 + m * 16 + r) * 32 + kq * 8]);
#pragma unroll
        for (int n = 0; n < 4; ++n)
            bf[n] = *reinterpret_cast<bf16x8*>(&ldsB[(wn * 64 + n * 16 + r) * 32 + kq * 8]);
#pragma unroll
        for (int m = 0; m < 4; ++m)
#pragma unroll
            for (int n = 0; n < 4; ++n)
                acc[m][n] = __builtin_amdgcn_mfma_f32_16x16x32_bf16(af[m], bf[n], acc[m][n], 0, 0, 0);
        __syncthreads();
    }

    int row0 = bm + wm * 64, col0 = bn + wn * 64;
#pragma unroll
    for (int m = 0; m < 4; ++m) {
#pragma unroll
        for (int n = 0; n < 4; ++n) {
            int col = col0 + n * 16 + r;
            if (col < N) {
#pragma unroll
                for (int rr = 0; rr < 4; ++rr) {
                    int row = row0 + m * 16 + kq * 4 + rr;
                    float v = acc[m][n][rr];
                    if (bias) v += bias[col];
                    if (flags & GF_GELU) v = gelu_tanh(v);
                    if (resid) v += resid[(size_t)row * N + col];
                    if (flags & GF_OBF16) ((bf16*)C)[(size_t)row * N + col] = (bf16)v;
                    else                  ((float*)C)[(size_t)row * N + col] = v;
                }
            }
        }
    }
}

// ---------------- causal attention (fp32), ctx out bf16 ----------------
__global__ void attn_kernel(const float* __restrict__ qkv, bf16* __restrict__ ctx) {
    int blk = blockIdx.x;                 // b*NHEADS*TSEQ + h*TSEQ + q
    int q = blk & (TSEQ - 1);
    int h = (blk >> 10) % NHEADS;
    int b = blk / (NHEADS * TSEQ);
    int tid = threadIdx.x;                // 0..63, one wave

    __shared__ float s[TSEQ];
    __shared__ float qs[64];

    const float* qp = qkv + ((size_t)(b * TSEQ + q)) * (3 * DM) + h * 64;
    qs[tid] = qp[tid];
    __syncthreads();

    float lmax = -INFINITY;
    for (int kk = tid; kk <= q; kk += 64) {
        const float* kp = qkv + ((size_t)(b * TSEQ + kk)) * (3 * DM) + DM + h * 64;
        float acc = 0.f;
#pragma unroll 8
        for (int d = 0; d < 64; ++d) acc += qs[d] * kp[d];
        acc *= 0.125f;
        s[kk] = acc;
        lmax = fmaxf(lmax, acc);
    }
    for (int o = 32; o; o >>= 1) lmax = fmaxf(lmax, __shfl_xor(lmax, o));

    float lsum = 0.f;
    for (int kk = tid; kk <= q; kk += 64) {
        float p = __expf(s[kk] - lmax);
        s[kk] = p;
        lsum += p;
    }
    for (int o = 32; o; o >>= 1) lsum += __shfl_xor(lsum, o);
    __syncthreads();

    float invsum = 1.0f / lsum;
    float acc = 0.f;
    int d = tid;
    for (int kk = 0; kk <= q; ++kk) {
        const float* vp = qkv + ((size_t)(b * TSEQ + kk)) * (3 * DM) + 2 * DM + h * 64;
        acc += s[kk] * vp[d];
    }
    ctx[((size_t)(b * TSEQ + q)) * DM + h * 64 + d] = (bf16)(acc * invsum);
}

// ---------------- loss ----------------
__global__ void loss1_kernel(const float* __restrict__ logits, const int* __restrict__ target,
                             float* __restrict__ nll) {
    int row = blockIdx.x, tid = threadIdx.x;
    const float* lr = logits + (size_t)row * VOCAB;
    float m = -INFINITY, ssum = 0.f;
    for (int v = tid; v < VOCAB; v += 256) {
        float l = lr[v];
        if (l > m) { ssum = ssum * __expf(m - l) + 1.0f; m = l; }
        else       { ssum += __expf(l - m); }
    }
    __shared__ float sm[256], ss[256];
    sm[tid] = m; ss[tid] = ssum; __syncthreads();
    for (int o = 128; o; o >>= 1) {
        if (tid < o) {
            float m2 = sm[tid + o], s2 = ss[tid + o];
            float mm = fmaxf(sm[tid], m2);
            ss[tid] = ss[tid] * __expf(sm[tid] - mm) + s2 * __expf(m2 - mm);
            sm[tid] = mm;
        }
        __syncthreads();
    }
    if (tid == 0) {
        float lse = sm[0] + logf(ss[0]);
        nll[row] = lse - lr[target[row]];
    }
}

__global__ void loss2_kernel(const float* __restrict__ nll, float* __restrict__ loss) {
    int tid = threadIdx.x;
    float s = 0.f;
    for (int i = tid; i < BT; i += 1024) s += nll[i];
    __shared__ float r[1024];
    r[tid] = s; __syncthreads();
    for (int o = 512; o; o >>= 1) { if (tid < o) r[tid] += r[tid + o]; __syncthreads(); }
    if (tid == 0) *loss = r[0] * (1.0f / BT);
}

// ---------------- launcher ----------------
extern "C" void kernel_launch(void* const* d_in, const int* in_sizes, int n_in,
                              void* d_out, int out_size, void* d_ws, size_t ws_size,
                              hipStream_t stream) {
    const int*   inp    = (const int*)  d_in[0];
    const int*   target = (const int*)  d_in[1];
    const float* wte    = (const float*)d_in[2];
    const float* wpe    = (const float*)d_in[3];
    const float* ln1_w  = (const float*)d_in[4];
    const float* ln1_b  = (const float*)d_in[5];
    const float* attn_w = (const float*)d_in[6];
    const float* attn_b = (const float*)d_in[7];
    const float* proj_w = (const float*)d_in[8];
    const float* proj_b = (const float*)d_in[9];
    const float* ln2_w  = (const float*)d_in[10];
    const float* ln2_b  = (const float*)d_in[11];
    const float* fc_w   = (const float*)d_in[12];
    const float* fc_b   = (const float*)d_in[13];
    const float* fc2_w  = (const float*)d_in[14];
    const float* fc2_b  = (const float*)d_in[15];
    const float* lnf_w  = (const float*)d_in[16];
    const float* lnf_b  = (const float*)d_in[17];
    float* out = (float*)d_out;

    // workspace carve-up
    char* p = (char*)d_ws;
    auto alloc = [&](size_t bytes) { char* q = p; p += (bytes + 255) & ~(size_t)255; return q; };
    float* x     = (float*)alloc((size_t)BT * DM * 4);
    float* qkv   = (float*)alloc((size_t)BT * 3 * DM * 4);
    float* nll   = (float*)alloc((size_t)BT * 4);
    bf16*  tmpb  = (bf16*) alloc((size_t)BT * DM * 2);
    bf16*  ctxb  = (bf16*) alloc((size_t)BT * DM * 2);
    bf16*  hb    = (bf16*) alloc((size_t)BT * 4 * DM * 2);
    bf16*  wteb  = (bf16*) alloc((size_t)VOCAB * DM * 2);
    bf16*  wqkvT = (bf16*) alloc((size_t)NLAYERS * 3 * DM * DM * 2);
    bf16*  wprojT= (bf16*) alloc((size_t)NLAYERS * DM * DM * 2);
    bf16*  wfcT  = (bf16*) alloc((size_t)NLAYERS * 4 * DM * DM * 2);
    bf16*  wfc2T = (bf16*) alloc((size_t)NLAYERS * 4 * DM * DM * 2);

    dim3 tb(32, 8);
    // weight prep: fp32 [K][N] -> bf16 [N][K]
    transpose_bf16_kernel<<<dim3(3 * DM / 32, DM / 32, NLAYERS), tb, 0, stream>>>(attn_w, wqkvT, DM, 3 * DM);
    transpose_bf16_kernel<<<dim3(DM / 32, DM / 32, NLAYERS), tb, 0, stream>>>(proj_w, wprojT, DM, DM);
    transpose_bf16_kernel<<<dim3(4 * DM / 32, DM / 32, NLAYERS), tb, 0, stream>>>(fc_w, wfcT, DM, 4 * DM);
    transpose_bf16_kernel<<<dim3(DM / 32, 4 * DM / 32, NLAYERS), tb, 0, stream>>>(fc2_w, wfc2T, 4 * DM, DM);
    {
        size_t n = (size_t)VOCAB * DM;
        tobf16_kernel<<<(unsigned)((n + 255) / 256), 256, 0, stream>>>(wte, wteb, n);
    }

    embed_kernel<<<BT * DM / 256, 256, 0, stream>>>(inp, wte, wpe, x);

    for (int i = 0; i < NLAYERS; ++i) {
        ln_kernel<<<BT, 256, 0, stream>>>(x, ln1_w + i * DM, ln1_b + i * DM, tmpb);
        gemm_bf16_kernel<<<dim3(3 * DM / 128, BT / 128), 256, 0, stream>>>(
            tmpb, wqkvT + (size_t)i * 3 * DM * DM, attn_b + i * 3 * DM, nullptr,
            qkv, BT, 3 * DM, DM, 0);
        attn_kernel<<<4 * NHEADS * TSEQ, 64, 0, stream>>>(qkv, ctxb);
        gemm_bf16_kernel<<<dim3(DM / 128, BT / 128), 256, 0, stream>>>(
            ctxb, wprojT + (size_t)i * DM * DM, proj_b + i * DM, x,
            x, BT, DM, DM, 0);
        ln_kernel<<<BT, 256, 0, stream>>>(x, ln2_w + i * DM, ln2_b + i * DM, tmpb);
        gemm_bf16_kernel<<<dim3(4 * DM / 128, BT / 128), 256, 0, stream>>>(
            tmpb, wfcT + (size_t)i * 4 * DM * DM, fc_b + i * 4 * DM, nullptr,
            hb, BT, 4 * DM, DM, GF_GELU | GF_OBF16);
        gemm_bf16_kernel<<<dim3(DM / 128, BT / 128), 256, 0, stream>>>(
            hb, wfc2T + (size_t)i * 4 * DM * DM, fc2_b + i * DM, x,
            x, BT, DM, 4 * DM, 0);
    }

    ln_kernel<<<BT, 256, 0, stream>>>(x, lnf_w, lnf_b, tmpb);
    gemm_bf16_kernel<<<dim3((VOCAB + 127) / 128, BT / 128), 256, 0, stream>>>(
        tmpb, wteb, nullptr, nullptr, out, BT, VOCAB, DM, GF_CLAMP);
    loss1_kernel<<<BT, 256, 0, stream>>>(out, target, nll);
    loss2_kernel<<<1, 1024, 0, stream>>>(nll, out + (size_t)out_size - 1);
}

// Round 3
// 5040.892 us; speedup vs baseline: 5.5982x; 3.4305x over previous
//
#include <hip/hip_runtime.h>
#include <hip/hip_bf16.h>
#include <cmath>

#define NLAYERS 12
#define NHEADS  12
#define DM      768
#define VOCAB   50257
#define TSEQ    1024
#define BT      4096   // B*T

typedef __attribute__((ext_vector_type(4))) float f32x4;
typedef __attribute__((ext_vector_type(8))) short bf16x8;

typedef __hip_bfloat16 bf16;

#define MFMA16(a, b, c) __builtin_amdgcn_mfma_f32_16x16x32_bf16(a, b, c, 0, 0, 0)

// ---------------- helpers ----------------
__device__ __forceinline__ void gload16(const void* g, void* l) {
    __builtin_amdgcn_global_load_lds(
        (const __attribute__((address_space(1))) void*)g,
        (__attribute__((address_space(3))) void*)l, 16, 0, 0);
}

__device__ __forceinline__ float gelu_tanh(float v) {
    float u = 0.7978845608028654f * (v + 0.044715f * v * v * v);
    return 0.5f * v * (1.0f + tanhf(u));
}

__device__ __forceinline__ short f2bf(float f) {
    bf16 h = (bf16)f;
    return *reinterpret_cast<short*>(&h);
}

// ---------------- weight prep ----------------
__global__ void transpose_bf16_kernel(const float* __restrict__ in, bf16* __restrict__ out,
                                      int K, int N) {
    __shared__ float tile[32][33];
    size_t lofs = (size_t)blockIdx.z * K * N;
    int k0 = blockIdx.y * 32, n0 = blockIdx.x * 32;
    int tx = threadIdx.x, ty = threadIdx.y;      // 32x8
#pragma unroll
    for (int i = 0; i < 32; i += 8)
        tile[ty + i][tx] = in[lofs + (size_t)(k0 + ty + i) * N + n0 + tx];
    __syncthreads();
#pragma unroll
    for (int i = 0; i < 32; i += 8)
        out[lofs + (size_t)(n0 + ty + i) * K + k0 + tx] = (bf16)tile[tx][ty + i];
}

__global__ void tobf16_kernel(const float* __restrict__ in, bf16* __restrict__ out, size_t n) {
    size_t i = (size_t)blockIdx.x * 256 + threadIdx.x;
    if (i < n) out[i] = (bf16)in[i];
}

// ---------------- embedding (fp32 residual stream) ----------------
__global__ void embed_kernel(const int* __restrict__ inp, const float* __restrict__ wte,
                             const float* __restrict__ wpe, float* __restrict__ x) {
    int idx = blockIdx.x * 256 + threadIdx.x;
    int m = idx / DM, c = idx % DM;
    int tok = inp[m];
    int t = m & (TSEQ - 1);
    x[idx] = wte[(size_t)tok * DM + c] + wpe[t * DM + c];
}

// ---------------- layernorm: fp32 in -> bf16 out ----------------
__global__ void ln_kernel(const float* __restrict__ x, const float* __restrict__ w,
                          const float* __restrict__ b, bf16* __restrict__ y) {
    int row = blockIdx.x, tid = threadIdx.x;
    const float* xr = x + (size_t)row * DM;
    float s = 0.f, q = 0.f;
    for (int c = tid; c < DM; c += 256) { float v = xr[c]; s += v; q += v * v; }
    __shared__ float rs[256], rq[256];
    rs[tid] = s; rq[tid] = q; __syncthreads();
    for (int o = 128; o; o >>= 1) {
        if (tid < o) { rs[tid] += rs[tid + o]; rq[tid] += rq[tid + o]; }
        __syncthreads();
    }
    float mu  = rs[0] * (1.0f / DM);
    float var = rq[0] * (1.0f / DM) - mu * mu;
    float inv = rsqrtf(var + 1e-5f);
    for (int c = tid; c < DM; c += 256)
        y[(size_t)row * DM + c] = (bf16)((xr[c] - mu) * inv * w[c] + b[c]);
}

// ---------------- bf16 MFMA GEMM ----------------
#define GF_GELU  1
#define GF_OBF16 2
#define GF_CLAMP 4
__global__ __launch_bounds__(256) void gemm_bf16_kernel(
    const bf16* __restrict__ A, const bf16* __restrict__ Bt,
    const float* __restrict__ bias, const float* __restrict__ resid,
    void* __restrict__ C, int M, int N, int K, int flags) {
    __shared__ short ldsA[128 * 32];
    __shared__ short ldsB[128 * 32];
    int tid = threadIdx.x;
    int lane = tid & 63, w = tid >> 6;
    int wm = w >> 1, wn = w & 1;
    int bm = blockIdx.y * 128, bn = blockIdx.x * 128;
    int r = lane & 15, kq = lane >> 4;

    f32x4 acc[4][4] = {};

    for (int k0 = 0; k0 < K; k0 += 32) {
#pragma unroll
        for (int i = 0; i < 2; ++i) {
            int chunk = i * 256 + tid;           // 16B chunk id
            int row = chunk >> 2, kqq = chunk & 3;
            const bf16* ga = A + (size_t)(bm + row) * K + k0 + kqq * 8;
            gload16(ga, ldsA + (size_t)(i * 256 + w * 64) * 8);
            int brow = bn + row;
            if (flags & GF_CLAMP) brow = min(brow, N - 1);
            const bf16* gb = Bt + (size_t)brow * K + k0 + kqq * 8;
            gload16(gb, ldsB + (size_t)(i * 256 + w * 64) * 8);
        }
        __syncthreads();

        bf16x8 af[4], bfr[4];
#pragma unroll
        for (int m = 0; m < 4; ++m)
            af[m] = *reinterpret_cast<bf16x8*>(&ldsA[(wm * 64 + m * 16 + r) * 32 + kq * 8]);
#pragma unroll
        for (int n = 0; n < 4; ++n)
            bfr[n] = *reinterpret_cast<bf16x8*>(&ldsB[(wn * 64 + n * 16 + r) * 32 + kq * 8]);
#pragma unroll
        for (int m = 0; m < 4; ++m)
#pragma unroll
            for (int n = 0; n < 4; ++n)
                acc[m][n] = MFMA16(af[m], bfr[n], acc[m][n]);
        __syncthreads();
    }

    int row0 = bm + wm * 64, col0 = bn + wn * 64;
#pragma unroll
    for (int m = 0; m < 4; ++m) {
#pragma unroll
        for (int n = 0; n < 4; ++n) {
            int col = col0 + n * 16 + r;
            if (col < N) {
#pragma unroll
                for (int rr = 0; rr < 4; ++rr) {
                    int row = row0 + m * 16 + kq * 4 + rr;
                    float v = acc[m][n][rr];
                    if (bias) v += bias[col];
                    if (flags & GF_GELU) v = gelu_tanh(v);
                    if (resid) v += resid[(size_t)row * N + col];
                    if (flags & GF_OBF16) ((bf16*)C)[(size_t)row * N + col] = (bf16)v;
                    else                  ((float*)C)[(size_t)row * N + col] = v;
                }
            }
        }
    }
}

// ---------------- flash attention (bf16 MFMA, online softmax) ----------------
// qkv: bf16 [BT][3*DM]. One block per (b,h,64-row q tile); 4 waves x 16 q-rows.
__global__ __launch_bounds__(256) void flash_attn_kernel(const bf16* __restrict__ qkv,
                                                         bf16* __restrict__ ctx) {
    __shared__ short Ks[64 * 64];        // K tile, 16B-chunk XOR-swizzled
    __shared__ short Vt[64][68];         // V^T tile, padded stride
    __shared__ short Ps[4][16][68];      // per-wave P tile, padded stride

    int tid = threadIdx.x, lane = tid & 63, w = tid >> 6;
    int r = lane & 15, kq = lane >> 4;
    int q0 = blockIdx.x * 64;
    int bh = blockIdx.y;
    int b = bh / NHEADS, h = bh % NHEADS;
    const int RS = 3 * DM;               // qkv row stride

    // Q fragments: row = q0 + w*16 + r, two 32-wide k tiles over d
    const bf16* qbase = qkv + (size_t)(b * TSEQ + q0 + w * 16 + r) * RS + h * 64;
    bf16x8 qf[2];
    qf[0] = *reinterpret_cast<const bf16x8*>(qbase + kq * 8);
    qf[1] = *reinterpret_cast<const bf16x8*>(qbase + 32 + kq * 8);

    f32x4 of[4] = {};                    // O accum: d-frags n=0..3; rows kq*4+rr
    float mrow[4] = {-INFINITY, -INFINITY, -INFINITY, -INFINITY};
    float lrow[4] = {};

    int ntiles = q0 / 64 + 1;
    for (int t = 0; t < ntiles; ++t) {
        int kv0 = t * 64;
        __syncthreads();                 // previous tile fully consumed
        // ---- stage K (global_load_lds, swizzled chunks) ----
        const bf16* kbase = qkv + (size_t)(b * TSEQ + kv0) * RS + DM + h * 64;
#pragma unroll
        for (int i = 0; i < 2; ++i) {
            int chunk = i * 256 + tid;   // linear dest chunk
            int row = chunk >> 3, cp = chunk & 7;
            int csrc = cp ^ (row & 7);
            gload16(kbase + (size_t)row * RS + csrc * 8, Ks + chunk * 8);
        }
        // ---- stage V transposed via registers ----
        const bf16* vbase = qkv + (size_t)(b * TSEQ + kv0) * RS + 2 * DM + h * 64;
#pragma unroll
        for (int i = 0; i < 2; ++i) {
            int chunk = i * 256 + tid;
            int kv = chunk >> 3, d0 = (chunk & 7) * 8;
            bf16x8 v = *reinterpret_cast<const bf16x8*>(vbase + (size_t)kv * RS + d0);
#pragma unroll
            for (int j = 0; j < 8; ++j) Vt[d0 + j][kv] = ((short*)&v)[j];
        }
        __syncthreads();

        // ---- QK^T: 8 MFMA ----
        f32x4 sf[4] = {};
#pragma unroll
        for (int n = 0; n < 4; ++n) {
            int row = n * 16 + r;
#pragma unroll
            for (int kt = 0; kt < 2; ++kt) {
                int chunk = (kt * 4 + kq) ^ (row & 7);
                bf16x8 kf = *reinterpret_cast<bf16x8*>(&Ks[row * 64 + chunk * 8]);
                sf[n] = MFMA16(qf[kt], kf, sf[n]);
            }
        }

        // ---- online softmax ----
        bool diag = (kv0 + 64 > q0);
        float alpha[4];
#pragma unroll
        for (int rr = 0; rr < 4; ++rr) {
            int qrow = q0 + w * 16 + kq * 4 + rr;
            float vals[4];
            float mx = mrow[rr];
#pragma unroll
            for (int n = 0; n < 4; ++n) {
                float v = sf[n][rr] * 0.125f;
                if (diag && (kv0 + n * 16 + r) > qrow) v = -INFINITY;
                vals[n] = v;
                mx = fmaxf(mx, v);
            }
#pragma unroll
            for (int o = 1; o < 16; o <<= 1) mx = fmaxf(mx, __shfl_xor(mx, o));
            float al = __expf(mrow[rr] - mx);
            float sum = 0.f;
#pragma unroll
            for (int n = 0; n < 4; ++n) {
                float p = __expf(vals[n] - mx);
                vals[n] = p;
                sum += p;
            }
#pragma unroll
            for (int o = 1; o < 16; o <<= 1) sum += __shfl_xor(sum, o);
            mrow[rr] = mx;
            lrow[rr] = lrow[rr] * al + sum;
            alpha[rr] = al;
#pragma unroll
            for (int n = 0; n < 4; ++n) Ps[w][kq * 4 + rr][n * 16 + r] = f2bf(vals[n]);
        }
#pragma unroll
        for (int n = 0; n < 4; ++n)
#pragma unroll
            for (int rr = 0; rr < 4; ++rr) of[n][rr] *= alpha[rr];

        // ---- PV: 8 MFMA (A = P from LDS, B = V^T from LDS) ----
#pragma unroll
        for (int kt = 0; kt < 2; ++kt) {
            bf16x8 pa = *reinterpret_cast<bf16x8*>(&Ps[w][r][kt * 32 + kq * 8]);
#pragma unroll
            for (int n = 0; n < 4; ++n) {
                bf16x8 vf = *reinterpret_cast<bf16x8*>(&Vt[n * 16 + r][kt * 32 + kq * 8]);
                of[n] = MFMA16(pa, vf, of[n]);
            }
        }
    }

    // ---- epilogue ----
#pragma unroll
    for (int rr = 0; rr < 4; ++rr) {
        float inv = 1.0f / lrow[rr];
        int qrow = q0 + w * 16 + kq * 4 + rr;
        bf16* cb = ctx + (size_t)(b * TSEQ + qrow) * DM + h * 64;
#pragma unroll
        for (int n = 0; n < 4; ++n) cb[n * 16 + r] = (bf16)(of[n][rr] * inv);
    }
}

// ---------------- loss ----------------
__global__ void loss1_kernel(const float* __restrict__ logits, const int* __restrict__ target,
                             float* __restrict__ nll) {
    int row = blockIdx.x, tid = threadIdx.x;
    const float* lr = logits + (size_t)row * VOCAB;
    float m = -INFINITY, ssum = 0.f;
    for (int v = tid; v < VOCAB; v += 256) {
        float l = lr[v];
        if (l > m) { ssum = ssum * __expf(m - l) + 1.0f; m = l; }
        else       { ssum += __expf(l - m); }
    }
    __shared__ float sm[256], ss[256];
    sm[tid] = m; ss[tid] = ssum; __syncthreads();
    for (int o = 128; o; o >>= 1) {
        if (tid < o) {
            float m2 = sm[tid + o], s2 = ss[tid + o];
            float mm = fmaxf(sm[tid], m2);
            ss[tid] = ss[tid] * __expf(sm[tid] - mm) + s2 * __expf(m2 - mm);
            sm[tid] = mm;
        }
        __syncthreads();
    }
    if (tid == 0) {
        float lse = sm[0] + logf(ss[0]);
        nll[row] = lse - lr[target[row]];
    }
}

__global__ void loss2_kernel(const float* __restrict__ nll, float* __restrict__ loss) {
    int tid = threadIdx.x;
    float s = 0.f;
    for (int i = tid; i < BT; i += 1024) s += nll[i];
    __shared__ float r[1024];
    r[tid] = s; __syncthreads();
    for (int o = 512; o; o >>= 1) { if (tid < o) r[tid] += r[tid + o]; __syncthreads(); }
    if (tid == 0) *loss = r[0] * (1.0f / BT);
}

// ---------------- launcher ----------------
extern "C" void kernel_launch(void* const* d_in, const int* in_sizes, int n_in,
                              void* d_out, int out_size, void* d_ws, size_t ws_size,
                              hipStream_t stream) {
    const int*   inp    = (const int*)  d_in[0];
    const int*   target = (const int*)  d_in[1];
    const float* wte    = (const float*)d_in[2];
    const float* wpe    = (const float*)d_in[3];
    const float* ln1_w  = (const float*)d_in[4];
    const float* ln1_b  = (const float*)d_in[5];
    const float* attn_w = (const float*)d_in[6];
    const float* attn_b = (const float*)d_in[7];
    const float* proj_w = (const float*)d_in[8];
    const float* proj_b = (const float*)d_in[9];
    const float* ln2_w  = (const float*)d_in[10];
    const float* ln2_b  = (const float*)d_in[11];
    const float* fc_w   = (const float*)d_in[12];
    const float* fc_b   = (const float*)d_in[13];
    const float* fc2_w  = (const float*)d_in[14];
    const float* fc2_b  = (const float*)d_in[15];
    const float* lnf_w  = (const float*)d_in[16];
    const float* lnf_b  = (const float*)d_in[17];
    float* out = (float*)d_out;

    // workspace carve-up
    char* p = (char*)d_ws;
    auto alloc = [&](size_t bytes) { char* q = p; p += (bytes + 255) & ~(size_t)255; return q; };
    float* x     = (float*)alloc((size_t)BT * DM * 4);
    float* nll   = (float*)alloc((size_t)BT * 4);
    bf16*  qkvb  = (bf16*) alloc((size_t)BT * 3 * DM * 2);
    bf16*  tmpb  = (bf16*) alloc((size_t)BT * DM * 2);
    bf16*  ctxb  = (bf16*) alloc((size_t)BT * DM * 2);
    bf16*  hb    = (bf16*) alloc((size_t)BT * 4 * DM * 2);
    bf16*  wteb  = (bf16*) alloc((size_t)VOCAB * DM * 2);
    bf16*  wqkvT = (bf16*) alloc((size_t)NLAYERS * 3 * DM * DM * 2);
    bf16*  wprojT= (bf16*) alloc((size_t)NLAYERS * DM * DM * 2);
    bf16*  wfcT  = (bf16*) alloc((size_t)NLAYERS * 4 * DM * DM * 2);
    bf16*  wfc2T = (bf16*) alloc((size_t)NLAYERS * 4 * DM * DM * 2);

    dim3 tb(32, 8);
    transpose_bf16_kernel<<<dim3(3 * DM / 32, DM / 32, NLAYERS), tb, 0, stream>>>(attn_w, wqkvT, DM, 3 * DM);
    transpose_bf16_kernel<<<dim3(DM / 32, DM / 32, NLAYERS), tb, 0, stream>>>(proj_w, wprojT, DM, DM);
    transpose_bf16_kernel<<<dim3(4 * DM / 32, DM / 32, NLAYERS), tb, 0, stream>>>(fc_w, wfcT, DM, 4 * DM);
    transpose_bf16_kernel<<<dim3(DM / 32, 4 * DM / 32, NLAYERS), tb, 0, stream>>>(fc2_w, wfc2T, 4 * DM, DM);
    {
        size_t n = (size_t)VOCAB * DM;
        tobf16_kernel<<<(unsigned)((n + 255) / 256), 256, 0, stream>>>(wte, wteb, n);
    }

    embed_kernel<<<BT * DM / 256, 256, 0, stream>>>(inp, wte, wpe, x);

    for (int i = 0; i < NLAYERS; ++i) {
        ln_kernel<<<BT, 256, 0, stream>>>(x, ln1_w + i * DM, ln1_b + i * DM, tmpb);
        gemm_bf16_kernel<<<dim3(3 * DM / 128, BT / 128), 256, 0, stream>>>(
            tmpb, wqkvT + (size_t)i * 3 * DM * DM, attn_b + i * 3 * DM, nullptr,
            qkvb, BT, 3 * DM, DM, GF_OBF16);
        flash_attn_kernel<<<dim3(TSEQ / 64, 4 * NHEADS), 256, 0, stream>>>(qkvb, ctxb);
        gemm_bf16_kernel<<<dim3(DM / 128, BT / 128), 256, 0, stream>>>(
            ctxb, wprojT + (size_t)i * DM * DM, proj_b + i * DM, x,
            x, BT, DM, DM, 0);
        ln_kernel<<<BT, 256, 0, stream>>>(x, ln2_w + i * DM, ln2_b + i * DM, tmpb);
        gemm_bf16_kernel<<<dim3(4 * DM / 128, BT / 128), 256, 0, stream>>>(
            tmpb, wfcT + (size_t)i * 4 * DM * DM, fc_b + i * 4 * DM, nullptr,
            hb, BT, 4 * DM, DM, GF_GELU | GF_OBF16);
        gemm_bf16_kernel<<<dim3(DM / 128, BT / 128), 256, 0, stream>>>(
            hb, wfc2T + (size_t)i * 4 * DM * DM, fc2_b + i * DM, x,
            x, BT, DM, 4 * DM, 0);
    }

    ln_kernel<<<BT, 256, 0, stream>>>(x, lnf_w, lnf_b, tmpb);
    gemm_bf16_kernel<<<dim3((VOCAB + 127) / 128, BT / 128), 256, 0, stream>>>(
        tmpb, wteb, nullptr, nullptr, out, BT, VOCAB, DM, GF_CLAMP);
    loss1_kernel<<<BT, 256, 0, stream>>>(out, target, nll);
    loss2_kernel<<<1, 1024, 0, stream>>>(nll, out + (size_t)out_size - 1);
}

// Round 4
// 4917.779 us; speedup vs baseline: 5.7384x; 1.0250x over previous
//
#include <hip/hip_runtime.h>
#include <hip/hip_bf16.h>
#include <cmath>

#define NLAYERS 12
#define NHEADS  12
#define DM      768
#define VOCAB   50257
#define TSEQ    1024
#define BT      4096   // B*T

typedef __attribute__((ext_vector_type(4))) float f32x4;
typedef __attribute__((ext_vector_type(8))) short bf16x8;

typedef __hip_bfloat16 bf16;

#define MFMA16(a, b, c) __builtin_amdgcn_mfma_f32_16x16x32_bf16(a, b, c, 0, 0, 0)

// ---------------- helpers ----------------
__device__ __forceinline__ void gload16(const void* g, void* l) {
    __builtin_amdgcn_global_load_lds(
        (const __attribute__((address_space(1))) void*)g,
        (__attribute__((address_space(3))) void*)l, 16, 0, 0);
}

__device__ __forceinline__ float gelu_tanh(float v) {
    float u = 0.7978845608028654f * (v + 0.044715f * v * v * v);
    return 0.5f * v * (1.0f + tanhf(u));
}

__device__ __forceinline__ short f2bf(float f) {
    bf16 h = (bf16)f;
    return *reinterpret_cast<short*>(&h);
}

struct ushort4s { short a, b, c, d; };

// ---------------- weight prep ----------------
__global__ void transpose_bf16_kernel(const float* __restrict__ in, bf16* __restrict__ out,
                                      int K, int N) {
    __shared__ float tile[32][33];
    size_t lofs = (size_t)blockIdx.z * K * N;
    int k0 = blockIdx.y * 32, n0 = blockIdx.x * 32;
    int tx = threadIdx.x, ty = threadIdx.y;      // 32x8
#pragma unroll
    for (int i = 0; i < 32; i += 8)
        tile[ty + i][tx] = in[lofs + (size_t)(k0 + ty + i) * N + n0 + tx];
    __syncthreads();
#pragma unroll
    for (int i = 0; i < 32; i += 8)
        out[lofs + (size_t)(n0 + ty + i) * K + k0 + tx] = (bf16)tile[tx][ty + i];
}

__global__ void tobf16_kernel(const float* __restrict__ in, bf16* __restrict__ out, size_t n) {
    size_t i = (size_t)blockIdx.x * 256 + threadIdx.x;
    if (i < n) out[i] = (bf16)in[i];
}

// ---------------- embedding (fp32 residual stream) ----------------
__global__ void embed_kernel(const int* __restrict__ inp, const float* __restrict__ wte,
                             const float* __restrict__ wpe, float* __restrict__ x) {
    int idx = blockIdx.x * 256 + threadIdx.x;
    int m = idx / DM, c = idx % DM;
    int tok = inp[m];
    int t = m & (TSEQ - 1);
    x[idx] = wte[(size_t)tok * DM + c] + wpe[t * DM + c];
}

// ---------------- layernorm: fp32 in -> bf16 out (vectorized) ----------------
__global__ __launch_bounds__(256) void ln_kernel(const float* __restrict__ x,
                                                 const float* __restrict__ w,
                                                 const float* __restrict__ b,
                                                 bf16* __restrict__ y) {
    int row = blockIdx.x, tid = threadIdx.x;     // 256 threads, 192 active for data
    const float4* xr = reinterpret_cast<const float4*>(x + (size_t)row * DM);
    float4 v = {0.f, 0.f, 0.f, 0.f};
    float s = 0.f, q = 0.f;
    if (tid < 192) {
        v = xr[tid];
        s = v.x + v.y + v.z + v.w;
        q = v.x * v.x + v.y * v.y + v.z * v.z + v.w * v.w;
    }
#pragma unroll
    for (int o = 1; o < 64; o <<= 1) { s += __shfl_xor(s, o); q += __shfl_xor(q, o); }
    __shared__ float ss[4], qq[4];
    if ((tid & 63) == 0) { ss[tid >> 6] = s; qq[tid >> 6] = q; }
    __syncthreads();
    s = ss[0] + ss[1] + ss[2] + ss[3];
    q = qq[0] + qq[1] + qq[2] + qq[3];
    float mu  = s * (1.0f / DM);
    float var = q * (1.0f / DM) - mu * mu;
    float inv = rsqrtf(var + 1e-5f);
    if (tid < 192) {
        float4 wv = reinterpret_cast<const float4*>(w)[tid];
        float4 bv = reinterpret_cast<const float4*>(b)[tid];
        ushort4s o;
        o.a = f2bf((v.x - mu) * inv * wv.x + bv.x);
        o.b = f2bf((v.y - mu) * inv * wv.y + bv.y);
        o.c = f2bf((v.z - mu) * inv * wv.z + bv.z);
        o.d = f2bf((v.w - mu) * inv * wv.w + bv.w);
        *reinterpret_cast<ushort4s*>(y + (size_t)row * DM + tid * 4) = o;
    }
}

// ---------------- bf16 MFMA GEMM ----------------
// C[M,N] = A[M,K] @ Bt[N,K]^T, fp32 accum. 128x128 tile, BK=32, 4 waves.
// Grid: x = M-blocks (fast axis -> weight-panel L2 reuse), y = N-blocks.
// LDS XOR swizzle (T2, rule #21): linear LDS dest, source granule ^= (row>>1)&3,
// read index granule ^= (row>>1)&3 -> rows 0..7 cover all 32 banks.
#define GF_GELU  1
#define GF_OBF16 2
#define GF_CLAMP 4
__global__ __launch_bounds__(256) void gemm_bf16_kernel(
    const bf16* __restrict__ A, const bf16* __restrict__ Bt,
    const float* __restrict__ bias, const float* __restrict__ resid,
    void* __restrict__ C, int M, int N, int K, int flags) {
    __shared__ short ldsA[128 * 32];
    __shared__ short ldsB[128 * 32];
    int tid = threadIdx.x;
    int lane = tid & 63, w = tid >> 6;
    int wm = w >> 1, wn = w & 1;
    int bm = blockIdx.x * 128, bn = blockIdx.y * 128;
    int r = lane & 15, kq = lane >> 4;

    f32x4 acc[4][4] = {};

    for (int k0 = 0; k0 < K; k0 += 32) {
#pragma unroll
        for (int i = 0; i < 2; ++i) {
            int chunk = i * 256 + tid;           // 16B chunk id = row*4 + dest granule
            int row = chunk >> 2;
            int gs = (chunk & 3) ^ ((row >> 1) & 3);   // swizzled source granule
            const bf16* ga = A + (size_t)(bm + row) * K + k0 + gs * 8;
            gload16(ga, ldsA + (size_t)(i * 256 + w * 64) * 8);
            int brow = bn + row;
            if (flags & GF_CLAMP) brow = min(brow, N - 1);
            const bf16* gb = Bt + (size_t)brow * K + k0 + gs * 8;
            gload16(gb, ldsB + (size_t)(i * 256 + w * 64) * 8);
        }
        __syncthreads();

        bf16x8 af[4], bfr[4];
#pragma unroll
        for (int m = 0; m < 4; ++m) {
            int row = wm * 64 + m * 16 + r;
            af[m] = *reinterpret_cast<bf16x8*>(&ldsA[row * 32 + (kq ^ ((row >> 1) & 3)) * 8]);
        }
#pragma unroll
        for (int n = 0; n < 4; ++n) {
            int row = wn * 64 + n * 16 + r;
            bfr[n] = *reinterpret_cast<bf16x8*>(&ldsB[row * 32 + (kq ^ ((row >> 1) & 3)) * 8]);
        }
#pragma unroll
        for (int m = 0; m < 4; ++m)
#pragma unroll
            for (int n = 0; n < 4; ++n)
                acc[m][n] = MFMA16(af[m], bfr[n], acc[m][n]);
        __syncthreads();
    }

    int row0 = bm + wm * 64, col0 = bn + wn * 64;
#pragma unroll
    for (int m = 0; m < 4; ++m) {
#pragma unroll
        for (int n = 0; n < 4; ++n) {
            int col = col0 + n * 16 + r;
            if (col < N) {
#pragma unroll
                for (int rr = 0; rr < 4; ++rr) {
                    int row = row0 + m * 16 + kq * 4 + rr;
                    float v = acc[m][n][rr];
                    if (bias) v += bias[col];
                    if (flags & GF_GELU) v = gelu_tanh(v);
                    if (resid) v += resid[(size_t)row * N + col];
                    if (flags & GF_OBF16) ((bf16*)C)[(size_t)row * N + col] = (bf16)v;
                    else                  ((float*)C)[(size_t)row * N + col] = v;
                }
            }
        }
    }
}

// ---------------- flash attention (bf16 MFMA, online softmax) ----------------
__global__ __launch_bounds__(256) void flash_attn_kernel(const bf16* __restrict__ qkv,
                                                         bf16* __restrict__ ctx) {
    __shared__ short Ks[64 * 64];        // K tile, 16B-chunk XOR-swizzled
    __shared__ short Vt[64][68];         // V^T tile, padded stride
    __shared__ short Ps[4][16][68];      // per-wave P tile, padded stride

    int tid = threadIdx.x, lane = tid & 63, w = tid >> 6;
    int r = lane & 15, kq = lane >> 4;
    int q0 = blockIdx.x * 64;
    int bh = blockIdx.y;
    int b = bh / NHEADS, h = bh % NHEADS;
    const int RS = 3 * DM;               // qkv row stride

    const bf16* qbase = qkv + (size_t)(b * TSEQ + q0 + w * 16 + r) * RS + h * 64;
    bf16x8 qf[2];
    qf[0] = *reinterpret_cast<const bf16x8*>(qbase + kq * 8);
    qf[1] = *reinterpret_cast<const bf16x8*>(qbase + 32 + kq * 8);

    f32x4 of[4] = {};
    float mrow[4] = {-INFINITY, -INFINITY, -INFINITY, -INFINITY};
    float lrow[4] = {};

    int ntiles = q0 / 64 + 1;
    for (int t = 0; t < ntiles; ++t) {
        int kv0 = t * 64;
        __syncthreads();
        const bf16* kbase = qkv + (size_t)(b * TSEQ + kv0) * RS + DM + h * 64;
#pragma unroll
        for (int i = 0; i < 2; ++i) {
            int chunk = i * 256 + tid;
            int row = chunk >> 3, cp = chunk & 7;
            int csrc = cp ^ (row & 7);
            gload16(kbase + (size_t)row * RS + csrc * 8, Ks + chunk * 8);
        }
        const bf16* vbase = qkv + (size_t)(b * TSEQ + kv0) * RS + 2 * DM + h * 64;
#pragma unroll
        for (int i = 0; i < 2; ++i) {
            int chunk = i * 256 + tid;
            int kv = chunk >> 3, d0 = (chunk & 7) * 8;
            bf16x8 v = *reinterpret_cast<const bf16x8*>(vbase + (size_t)kv * RS + d0);
#pragma unroll
            for (int j = 0; j < 8; ++j) Vt[d0 + j][kv] = ((short*)&v)[j];
        }
        __syncthreads();

        f32x4 sf[4] = {};
#pragma unroll
        for (int n = 0; n < 4; ++n) {
            int row = n * 16 + r;
#pragma unroll
            for (int kt = 0; kt < 2; ++kt) {
                int chunk = (kt * 4 + kq) ^ (row & 7);
                bf16x8 kf = *reinterpret_cast<bf16x8*>(&Ks[row * 64 + chunk * 8]);
                sf[n] = MFMA16(qf[kt], kf, sf[n]);
            }
        }

        bool diag = (kv0 + 64 > q0);
        float alpha[4];
#pragma unroll
        for (int rr = 0; rr < 4; ++rr) {
            int qrow = q0 + w * 16 + kq * 4 + rr;
            float vals[4];
            float mx = mrow[rr];
#pragma unroll
            for (int n = 0; n < 4; ++n) {
                float v = sf[n][rr] * 0.125f;
                if (diag && (kv0 + n * 16 + r) > qrow) v = -INFINITY;
                vals[n] = v;
                mx = fmaxf(mx, v);
            }
#pragma unroll
            for (int o = 1; o < 16; o <<= 1) mx = fmaxf(mx, __shfl_xor(mx, o));
            float al = __expf(mrow[rr] - mx);
            float sum = 0.f;
#pragma unroll
            for (int n = 0; n < 4; ++n) {
                float p = __expf(vals[n] - mx);
                vals[n] = p;
                sum += p;
            }
#pragma unroll
            for (int o = 1; o < 16; o <<= 1) sum += __shfl_xor(sum, o);
            mrow[rr] = mx;
            lrow[rr] = lrow[rr] * al + sum;
            alpha[rr] = al;
#pragma unroll
            for (int n = 0; n < 4; ++n) Ps[w][kq * 4 + rr][n * 16 + r] = f2bf(vals[n]);
        }
#pragma unroll
        for (int n = 0; n < 4; ++n)
#pragma unroll
            for (int rr = 0; rr < 4; ++rr) of[n][rr] *= alpha[rr];

#pragma unroll
        for (int kt = 0; kt < 2; ++kt) {
            bf16x8 pa = *reinterpret_cast<bf16x8*>(&Ps[w][r][kt * 32 + kq * 8]);
#pragma unroll
            for (int n = 0; n < 4; ++n) {
                bf16x8 vf = *reinterpret_cast<bf16x8*>(&Vt[n * 16 + r][kt * 32 + kq * 8]);
                of[n] = MFMA16(pa, vf, of[n]);
            }
        }
    }

#pragma unroll
    for (int rr = 0; rr < 4; ++rr) {
        float inv = 1.0f / lrow[rr];
        int qrow = q0 + w * 16 + kq * 4 + rr;
        bf16* cb = ctx + (size_t)(b * TSEQ + qrow) * DM + h * 64;
#pragma unroll
        for (int n = 0; n < 4; ++n) cb[n * 16 + r] = (bf16)(of[n][rr] * inv);
    }
}

// ---------------- loss ----------------
__global__ __launch_bounds__(256) void loss1_kernel(const float* __restrict__ logits,
                                                    const int* __restrict__ target,
                                                    float* __restrict__ nll) {
    int row = blockIdx.x, tid = threadIdx.x;
    const float* lr = logits + (size_t)row * VOCAB;
    const float4* lr4 = reinterpret_cast<const float4*>(lr);
    float m = -INFINITY, ssum = 0.f;
    for (int i = tid; i < VOCAB / 4; i += 256) {      // 12564 float4s
        float4 f = lr4[i];
        float vv[4] = {f.x, f.y, f.z, f.w};
#pragma unroll
        for (int j = 0; j < 4; ++j) {
            float l = vv[j];
            if (l > m) { ssum = ssum * __expf(m - l) + 1.0f; m = l; }
            else       { ssum += __expf(l - m); }
        }
    }
    if (tid == 0) {                                   // tail: VOCAB%4 == 1
        float l = lr[VOCAB - 1];
        if (l > m) { ssum = ssum * __expf(m - l) + 1.0f; m = l; }
        else       { ssum += __expf(l - m); }
    }
    __shared__ float sm[256], ss[256];
    sm[tid] = m; ss[tid] = ssum; __syncthreads();
    for (int o = 128; o; o >>= 1) {
        if (tid < o) {
            float m2 = sm[tid + o], s2 = ss[tid + o];
            float mm = fmaxf(sm[tid], m2);
            ss[tid] = ss[tid] * __expf(sm[tid] - mm) + s2 * __expf(m2 - mm);
            sm[tid] = mm;
        }
        __syncthreads();
    }
    if (tid == 0) {
        float lse = sm[0] + logf(ss[0]);
        nll[row] = lse - lr[target[row]];
    }
}

__global__ void loss2_kernel(const float* __restrict__ nll, float* __restrict__ loss) {
    int tid = threadIdx.x;
    float s = 0.f;
    for (int i = tid; i < BT; i += 1024) s += nll[i];
    __shared__ float r[1024];
    r[tid] = s; __syncthreads();
    for (int o = 512; o; o >>= 1) { if (tid < o) r[tid] += r[tid + o]; __syncthreads(); }
    if (tid == 0) *loss = r[0] * (1.0f / BT);
}

// ---------------- launcher ----------------
extern "C" void kernel_launch(void* const* d_in, const int* in_sizes, int n_in,
                              void* d_out, int out_size, void* d_ws, size_t ws_size,
                              hipStream_t stream) {
    const int*   inp    = (const int*)  d_in[0];
    const int*   target = (const int*)  d_in[1];
    const float* wte    = (const float*)d_in[2];
    const float* wpe    = (const float*)d_in[3];
    const float* ln1_w  = (const float*)d_in[4];
    const float* ln1_b  = (const float*)d_in[5];
    const float* attn_w = (const float*)d_in[6];
    const float* attn_b = (const float*)d_in[7];
    const float* proj_w = (const float*)d_in[8];
    const float* proj_b = (const float*)d_in[9];
    const float* ln2_w  = (const float*)d_in[10];
    const float* ln2_b  = (const float*)d_in[11];
    const float* fc_w   = (const float*)d_in[12];
    const float* fc_b   = (const float*)d_in[13];
    const float* fc2_w  = (const float*)d_in[14];
    const float* fc2_b  = (const float*)d_in[15];
    const float* lnf_w  = (const float*)d_in[16];
    const float* lnf_b  = (const float*)d_in[17];
    float* out = (float*)d_out;

    char* p = (char*)d_ws;
    auto alloc = [&](size_t bytes) { char* q = p; p += (bytes + 255) & ~(size_t)255; return q; };
    float* x     = (float*)alloc((size_t)BT * DM * 4);
    float* nll   = (float*)alloc((size_t)BT * 4);
    bf16*  qkvb  = (bf16*) alloc((size_t)BT * 3 * DM * 2);
    bf16*  tmpb  = (bf16*) alloc((size_t)BT * DM * 2);
    bf16*  ctxb  = (bf16*) alloc((size_t)BT * DM * 2);
    bf16*  hb    = (bf16*) alloc((size_t)BT * 4 * DM * 2);
    bf16*  wteb  = (bf16*) alloc((size_t)VOCAB * DM * 2);
    bf16*  wqkvT = (bf16*) alloc((size_t)NLAYERS * 3 * DM * DM * 2);
    bf16*  wprojT= (bf16*) alloc((size_t)NLAYERS * DM * DM * 2);
    bf16*  wfcT  = (bf16*) alloc((size_t)NLAYERS * 4 * DM * DM * 2);
    bf16*  wfc2T = (bf16*) alloc((size_t)NLAYERS * 4 * DM * DM * 2);

    dim3 tb(32, 8);
    transpose_bf16_kernel<<<dim3(3 * DM / 32, DM / 32, NLAYERS), tb, 0, stream>>>(attn_w, wqkvT, DM, 3 * DM);
    transpose_bf16_kernel<<<dim3(DM / 32, DM / 32, NLAYERS), tb, 0, stream>>>(proj_w, wprojT, DM, DM);
    transpose_bf16_kernel<<<dim3(4 * DM / 32, DM / 32, NLAYERS), tb, 0, stream>>>(fc_w, wfcT, DM, 4 * DM);
    transpose_bf16_kernel<<<dim3(DM / 32, 4 * DM / 32, NLAYERS), tb, 0, stream>>>(fc2_w, wfc2T, 4 * DM, DM);
    {
        size_t n = (size_t)VOCAB * DM;
        tobf16_kernel<<<(unsigned)((n + 255) / 256), 256, 0, stream>>>(wte, wteb, n);
    }

    embed_kernel<<<BT * DM / 256, 256, 0, stream>>>(inp, wte, wpe, x);

    for (int i = 0; i < NLAYERS; ++i) {
        ln_kernel<<<BT, 256, 0, stream>>>(x, ln1_w + i * DM, ln1_b + i * DM, tmpb);
        gemm_bf16_kernel<<<dim3(BT / 128, 3 * DM / 128), 256, 0, stream>>>(
            tmpb, wqkvT + (size_t)i * 3 * DM * DM, attn_b + i * 3 * DM, nullptr,
            qkvb, BT, 3 * DM, DM, GF_OBF16);
        flash_attn_kernel<<<dim3(TSEQ / 64, 4 * NHEADS), 256, 0, stream>>>(qkvb, ctxb);
        gemm_bf16_kernel<<<dim3(BT / 128, DM / 128), 256, 0, stream>>>(
            ctxb, wprojT + (size_t)i * DM * DM, proj_b + i * DM, x,
            x, BT, DM, DM, 0);
        ln_kernel<<<BT, 256, 0, stream>>>(x, ln2_w + i * DM, ln2_b + i * DM, tmpb);
        gemm_bf16_kernel<<<dim3(BT / 128, 4 * DM / 128), 256, 0, stream>>>(
            tmpb, wfcT + (size_t)i * 4 * DM * DM, fc_b + i * 4 * DM, nullptr,
            hb, BT, 4 * DM, DM, GF_GELU | GF_OBF16);
        gemm_bf16_kernel<<<dim3(BT / 128, DM / 128), 256, 0, stream>>>(
            hb, wfc2T + (size_t)i * 4 * DM * DM, fc2_b + i * DM, x,
            x, BT, DM, 4 * DM, 0);
    }

    ln_kernel<<<BT, 256, 0, stream>>>(x, lnf_w, lnf_b, tmpb);
    gemm_bf16_kernel<<<dim3(BT / 128, (VOCAB + 127) / 128), 256, 0, stream>>>(
        tmpb, wteb, nullptr, nullptr, out, BT, VOCAB, DM, GF_CLAMP);
    loss1_kernel<<<BT, 256, 0, stream>>>(out, target, nll);
    loss2_kernel<<<1, 1024, 0, stream>>>(nll, out + (size_t)out_size - 1);
}

// Round 5
// 4701.277 us; speedup vs baseline: 6.0026x; 1.0461x over previous
//
#include <hip/hip_runtime.h>
#include <hip/hip_bf16.h>
#include <cmath>

#define NLAYERS 12
#define NHEADS  12
#define DM      768
#define VOCAB   50257
#define TSEQ    1024
#define BT      4096   // B*T
#define NCHUNK  786    // ceil(VOCAB/64) col-chunks for loss partials

typedef __attribute__((ext_vector_type(4))) float f32x4;
typedef __attribute__((ext_vector_type(8))) short bf16x8;

typedef __hip_bfloat16 bf16;

#define MFMA16(a, b, c) __builtin_amdgcn_mfma_f32_16x16x32_bf16(a, b, c, 0, 0, 0)

// ---------------- helpers ----------------
__device__ __forceinline__ void gload16(const void* g, void* l) {
    __builtin_amdgcn_global_load_lds(
        (const __attribute__((address_space(1))) void*)g,
        (__attribute__((address_space(3))) void*)l, 16, 0, 0);
}

__device__ __forceinline__ float gelu_tanh(float v) {
    float u = 0.7978845608028654f * (v + 0.044715f * v * v * v);
    return 0.5f * v * (1.0f + tanhf(u));
}

__device__ __forceinline__ short f2bf(float f) {
    bf16 h = (bf16)f;
    return *reinterpret_cast<short*>(&h);
}

struct ushort4s { short a, b, c, d; };

// ---------------- weight prep ----------------
__global__ void transpose_bf16_kernel(const float* __restrict__ in, bf16* __restrict__ out,
                                      int K, int N) {
    __shared__ float tile[32][33];
    size_t lofs = (size_t)blockIdx.z * K * N;
    int k0 = blockIdx.y * 32, n0 = blockIdx.x * 32;
    int tx = threadIdx.x, ty = threadIdx.y;      // 32x8
#pragma unroll
    for (int i = 0; i < 32; i += 8)
        tile[ty + i][tx] = in[lofs + (size_t)(k0 + ty + i) * N + n0 + tx];
    __syncthreads();
#pragma unroll
    for (int i = 0; i < 32; i += 8)
        out[lofs + (size_t)(n0 + ty + i) * K + k0 + tx] = (bf16)tile[tx][ty + i];
}

__global__ void tobf16_kernel(const float* __restrict__ in, bf16* __restrict__ out, size_t n) {
    size_t i = (size_t)blockIdx.x * 256 + threadIdx.x;
    if (i < n) out[i] = (bf16)in[i];
}

// ---------------- embedding (fp32 residual stream, float4) ----------------
__global__ void embed_kernel(const int* __restrict__ inp, const float* __restrict__ wte,
                             const float* __restrict__ wpe, float* __restrict__ x) {
    int idx = blockIdx.x * 256 + threadIdx.x;    // over BT*DM/4
    int m = idx / (DM / 4), c4 = idx % (DM / 4);
    int tok = inp[m];
    int t = m & (TSEQ - 1);
    float4 a = reinterpret_cast<const float4*>(wte)[(size_t)tok * (DM / 4) + c4];
    float4 b = reinterpret_cast<const float4*>(wpe)[(size_t)t * (DM / 4) + c4];
    float4 o = {a.x + b.x, a.y + b.y, a.z + b.z, a.w + b.w};
    reinterpret_cast<float4*>(x)[idx] = o;
}

// ---------------- layernorm: fp32 in -> bf16 out (vectorized) ----------------
__global__ __launch_bounds__(256) void ln_kernel(const float* __restrict__ x,
                                                 const float* __restrict__ w,
                                                 const float* __restrict__ b,
                                                 bf16* __restrict__ y) {
    int row = blockIdx.x, tid = threadIdx.x;     // 256 threads, 192 active for data
    const float4* xr = reinterpret_cast<const float4*>(x + (size_t)row * DM);
    float4 v = {0.f, 0.f, 0.f, 0.f};
    float s = 0.f, q = 0.f;
    if (tid < 192) {
        v = xr[tid];
        s = v.x + v.y + v.z + v.w;
        q = v.x * v.x + v.y * v.y + v.z * v.z + v.w * v.w;
    }
#pragma unroll
    for (int o = 1; o < 64; o <<= 1) { s += __shfl_xor(s, o); q += __shfl_xor(q, o); }
    __shared__ float ss[4], qq[4];
    if ((tid & 63) == 0) { ss[tid >> 6] = s; qq[tid >> 6] = q; }
    __syncthreads();
    s = ss[0] + ss[1] + ss[2] + ss[3];
    q = qq[0] + qq[1] + qq[2] + qq[3];
    float mu  = s * (1.0f / DM);
    float var = q * (1.0f / DM) - mu * mu;
    float inv = rsqrtf(var + 1e-5f);
    if (tid < 192) {
        float4 wv = reinterpret_cast<const float4*>(w)[tid];
        float4 bv = reinterpret_cast<const float4*>(b)[tid];
        ushort4s o;
        o.a = f2bf((v.x - mu) * inv * wv.x + bv.x);
        o.b = f2bf((v.y - mu) * inv * wv.y + bv.y);
        o.c = f2bf((v.z - mu) * inv * wv.z + bv.z);
        o.d = f2bf((v.w - mu) * inv * wv.w + bv.w);
        *reinterpret_cast<ushort4s*>(y + (size_t)row * DM + tid * 4) = o;
    }
}

// ---------------- bf16 MFMA GEMM ----------------
// C[M,N] = A[M,K] @ Bt[N,K]^T, fp32 accum. 128x128 tile, BK=32, 4 waves.
// Grid: x = M-blocks (fast -> weight-panel L2 reuse), y = N-blocks.
#define GF_GELU    1
#define GF_OBF16   2
#define GF_CLAMP   4
#define GF_PARTIAL 8   // emit per-(row, 64-col-chunk) (max, sumexp) partials for loss
__global__ __launch_bounds__(256) void gemm_bf16_kernel(
    const bf16* __restrict__ A, const bf16* __restrict__ Bt,
    const float* __restrict__ bias, const float* __restrict__ resid,
    void* __restrict__ C, float2* __restrict__ partials,
    int M, int N, int K, int flags) {
    __shared__ short ldsA[128 * 32];
    __shared__ short ldsB[128 * 32];
    int tid = threadIdx.x;
    int lane = tid & 63, w = tid >> 6;
    int wm = w >> 1, wn = w & 1;
    int bm = blockIdx.x * 128, bn = blockIdx.y * 128;
    int r = lane & 15, kq = lane >> 4;

    f32x4 acc[4][4] = {};

    for (int k0 = 0; k0 < K; k0 += 32) {
#pragma unroll
        for (int i = 0; i < 2; ++i) {
            int chunk = i * 256 + tid;           // 16B chunk id = row*4 + dest granule
            int row = chunk >> 2;
            int gs = (chunk & 3) ^ ((row >> 1) & 3);   // swizzled source granule
            const bf16* ga = A + (size_t)(bm + row) * K + k0 + gs * 8;
            gload16(ga, ldsA + (size_t)(i * 256 + w * 64) * 8);
            int brow = bn + row;
            if (flags & GF_CLAMP) brow = min(brow, N - 1);
            const bf16* gb = Bt + (size_t)brow * K + k0 + gs * 8;
            gload16(gb, ldsB + (size_t)(i * 256 + w * 64) * 8);
        }
        __syncthreads();

        bf16x8 af[4], bfr[4];
#pragma unroll
        for (int m = 0; m < 4; ++m) {
            int row = wm * 64 + m * 16 + r;
            af[m] = *reinterpret_cast<bf16x8*>(&ldsA[row * 32 + (kq ^ ((row >> 1) & 3)) * 8]);
        }
#pragma unroll
        for (int n = 0; n < 4; ++n) {
            int row = wn * 64 + n * 16 + r;
            bfr[n] = *reinterpret_cast<bf16x8*>(&ldsB[row * 32 + (kq ^ ((row >> 1) & 3)) * 8]);
        }
#pragma unroll
        for (int m = 0; m < 4; ++m)
#pragma unroll
            for (int n = 0; n < 4; ++n)
                acc[m][n] = MFMA16(af[m], bfr[n], acc[m][n]);
        __syncthreads();
    }

    int row0 = bm + wm * 64, col0 = bn + wn * 64;
#pragma unroll
    for (int m = 0; m < 4; ++m) {
#pragma unroll
        for (int n = 0; n < 4; ++n) {
            int col = col0 + n * 16 + r;
            if (col < N) {
#pragma unroll
                for (int rr = 0; rr < 4; ++rr) {
                    int row = row0 + m * 16 + kq * 4 + rr;
                    float v = acc[m][n][rr];
                    if (bias) v += bias[col];
                    if (flags & GF_GELU) v = gelu_tanh(v);
                    if (resid) v += resid[(size_t)row * N + col];
                    if (flags & GF_OBF16) ((bf16*)C)[(size_t)row * N + col] = (bf16)v;
                    else                  ((float*)C)[(size_t)row * N + col] = v;
                }
            }
        }
    }

    if (flags & GF_PARTIAL) {
        int chunk = blockIdx.y * 2 + wn;          // 64-col chunk index
#pragma unroll
        for (int m = 0; m < 4; ++m) {
#pragma unroll
            for (int rr = 0; rr < 4; ++rr) {
                float vals[4], mx = -INFINITY;
#pragma unroll
                for (int n = 0; n < 4; ++n) {
                    int col = col0 + n * 16 + r;
                    float v = (col < N) ? acc[m][n][rr] : -INFINITY;
                    vals[n] = v;
                    mx = fmaxf(mx, v);
                }
#pragma unroll
                for (int o = 1; o < 16; o <<= 1) mx = fmaxf(mx, __shfl_xor(mx, o));
                float sum = 0.f;
#pragma unroll
                for (int n = 0; n < 4; ++n)
                    if (vals[n] > -INFINITY) sum += __expf(vals[n] - mx);
#pragma unroll
                for (int o = 1; o < 16; o <<= 1) sum += __shfl_xor(sum, o);
                if (r == 0) {
                    int row = row0 + m * 16 + kq * 4 + rr;
                    partials[(size_t)row * NCHUNK + chunk] = make_float2(mx, sum);
                }
            }
        }
    }
}

// ---------------- flash attention (bf16 MFMA, online softmax) ----------------
// QBLK=64 (4 waves x 16 q-rows), KVBLK=128 (two 64-tiles per barrier round).
__global__ __launch_bounds__(256) void flash_attn_kernel(const bf16* __restrict__ qkv,
                                                         bf16* __restrict__ ctx) {
    __shared__ short Ks[128 * 64];       // K tile, 16B-chunk XOR-swizzled
    __shared__ short Vt[64][132];        // V^T tile  [d][kv], padded stride
    __shared__ short Ps[4][16][132];     // per-wave P tile [qrow][kv], padded stride

    int tid = threadIdx.x, lane = tid & 63, w = tid >> 6;
    int r = lane & 15, kq = lane >> 4;
    int q0 = blockIdx.x * 64;
    int bh = blockIdx.y;
    int b = bh / NHEADS, h = bh % NHEADS;
    const int RS = 3 * DM;               // qkv row stride

    const bf16* qbase = qkv + (size_t)(b * TSEQ + q0 + w * 16 + r) * RS + h * 64;
    bf16x8 qf[2];
    qf[0] = *reinterpret_cast<const bf16x8*>(qbase + kq * 8);
    qf[1] = *reinterpret_cast<const bf16x8*>(qbase + 32 + kq * 8);

    f32x4 of[4] = {};
    float mrow[4] = {-INFINITY, -INFINITY, -INFINITY, -INFINITY};
    float lrow[4] = {};

    int ntiles = (blockIdx.x >> 1) + 1;
    for (int t = 0; t < ntiles; ++t) {
        int kv0 = t * 128;
        __syncthreads();
        // ---- stage K [128][64] (global_load_lds, swizzled granules) ----
        const bf16* kbase = qkv + (size_t)(b * TSEQ + kv0) * RS + DM + h * 64;
#pragma unroll
        for (int i = 0; i < 4; ++i) {
            int chunk = i * 256 + tid;
            int row = chunk >> 3, cp = chunk & 7;
            int csrc = cp ^ (row & 7);
            gload16(kbase + (size_t)row * RS + csrc * 8, Ks + chunk * 8);
        }
        // ---- stage V transposed via registers: Vt[d][kv] ----
        const bf16* vbase = qkv + (size_t)(b * TSEQ + kv0) * RS + 2 * DM + h * 64;
#pragma unroll
        for (int i = 0; i < 4; ++i) {
            int chunk = i * 256 + tid;
            int kv = chunk >> 3, d0 = (chunk & 7) * 8;
            bf16x8 v = *reinterpret_cast<const bf16x8*>(vbase + (size_t)kv * RS + d0);
#pragma unroll
            for (int j = 0; j < 8; ++j) Vt[d0 + j][kv] = ((short*)&v)[j];
        }
        __syncthreads();

        // ---- QK^T: 16 MFMA (8 kv-frags x 2 k-halves) ----
        f32x4 sf[8];
#pragma unroll
        for (int n = 0; n < 8; ++n) sf[n] = (f32x4){0.f, 0.f, 0.f, 0.f};
        __builtin_amdgcn_s_setprio(1);
#pragma unroll
        for (int n = 0; n < 8; ++n) {
            int row = n * 16 + r;
#pragma unroll
            for (int kt = 0; kt < 2; ++kt) {
                int gran = (kt * 4 + kq) ^ (row & 7);
                bf16x8 kf = *reinterpret_cast<bf16x8*>(&Ks[row * 64 + gran * 8]);
                sf[n] = MFMA16(qf[kt], kf, sf[n]);
            }
        }
        __builtin_amdgcn_s_setprio(0);

        // ---- online softmax over 128 cols ----
        bool diag = (kv0 + 128 > q0);
        float alpha[4];
#pragma unroll
        for (int rr = 0; rr < 4; ++rr) {
            int qrow = q0 + w * 16 + kq * 4 + rr;
            float vals[8];
            float mx = mrow[rr];
#pragma unroll
            for (int n = 0; n < 8; ++n) {
                float v = sf[n][rr] * 0.125f;
                if (diag && (kv0 + n * 16 + r) > qrow) v = -INFINITY;
                vals[n] = v;
                mx = fmaxf(mx, v);
            }
#pragma unroll
            for (int o = 1; o < 16; o <<= 1) mx = fmaxf(mx, __shfl_xor(mx, o));
            float al = __expf(mrow[rr] - mx);
            float sum = 0.f;
#pragma unroll
            for (int n = 0; n < 8; ++n) {
                float p = __expf(vals[n] - mx);
                vals[n] = p;
                sum += p;
            }
#pragma unroll
            for (int o = 1; o < 16; o <<= 1) sum += __shfl_xor(sum, o);
            mrow[rr] = mx;
            lrow[rr] = lrow[rr] * al + sum;
            alpha[rr] = al;
#pragma unroll
            for (int n = 0; n < 8; ++n) Ps[w][kq * 4 + rr][n * 16 + r] = f2bf(vals[n]);
        }
#pragma unroll
        for (int n = 0; n < 4; ++n)
#pragma unroll
            for (int rr = 0; rr < 4; ++rr) of[n][rr] *= alpha[rr];

        // ---- PV: 16 MFMA (4 k-quarters x 4 d-frags) ----
        __builtin_amdgcn_s_setprio(1);
#pragma unroll
        for (int kt = 0; kt < 4; ++kt) {
            bf16x8 pa = *reinterpret_cast<bf16x8*>(&Ps[w][r][kt * 32 + kq * 8]);
#pragma unroll
            for (int n = 0; n < 4; ++n) {
                bf16x8 vf = *reinterpret_cast<bf16x8*>(&Vt[n * 16 + r][kt * 32 + kq * 8]);
                of[n] = MFMA16(pa, vf, of[n]);
            }
        }
        __builtin_amdgcn_s_setprio(0);
    }

    // ---- epilogue ----
#pragma unroll
    for (int rr = 0; rr < 4; ++rr) {
        float inv = 1.0f / lrow[rr];
        int qrow = q0 + w * 16 + kq * 4 + rr;
        bf16* cb = ctx + (size_t)(b * TSEQ + qrow) * DM + h * 64;
#pragma unroll
        for (int n = 0; n < 4; ++n) cb[n * 16 + r] = (bf16)(of[n][rr] * inv);
    }
}

// ---------------- loss: merge per-chunk partials ----------------
__global__ __launch_bounds__(256) void loss_reduce_kernel(const float2* __restrict__ partials,
                                                          const float* __restrict__ logits,
                                                          const int* __restrict__ target,
                                                          float* __restrict__ nll) {
    int row = blockIdx.x, tid = threadIdx.x;
    const float2* pr = partials + (size_t)row * NCHUNK;
    float m = -INFINITY, s = 0.f;
    for (int c = tid; c < NCHUNK; c += 256) {
        float2 p = pr[c];
        if (p.x > m) { s = s * __expf(m - p.x) + p.y; m = p.x; }
        else         { s += p.y * __expf(p.x - m); }
    }
    __shared__ float sm[256], ssum[256];
    sm[tid] = m; ssum[tid] = s; __syncthreads();
    for (int o = 128; o; o >>= 1) {
        if (tid < o) {
            float m2 = sm[tid + o], s2 = ssum[tid + o];
            float mm = fmaxf(sm[tid], m2);
            ssum[tid] = ssum[tid] * __expf(sm[tid] - mm) + s2 * __expf(m2 - mm);
            sm[tid] = mm;
        }
        __syncthreads();
    }
    if (tid == 0) {
        float lse = sm[0] + logf(ssum[0]);
        nll[row] = lse - logits[(size_t)row * VOCAB + target[row]];
    }
}

__global__ void loss2_kernel(const float* __restrict__ nll, float* __restrict__ loss) {
    int tid = threadIdx.x;
    float s = 0.f;
    for (int i = tid; i < BT; i += 1024) s += nll[i];
    __shared__ float r[1024];
    r[tid] = s; __syncthreads();
    for (int o = 512; o; o >>= 1) { if (tid < o) r[tid] += r[tid + o]; __syncthreads(); }
    if (tid == 0) *loss = r[0] * (1.0f / BT);
}

// ---------------- launcher ----------------
extern "C" void kernel_launch(void* const* d_in, const int* in_sizes, int n_in,
                              void* d_out, int out_size, void* d_ws, size_t ws_size,
                              hipStream_t stream) {
    const int*   inp    = (const int*)  d_in[0];
    const int*   target = (const int*)  d_in[1];
    const float* wte    = (const float*)d_in[2];
    const float* wpe    = (const float*)d_in[3];
    const float* ln1_w  = (const float*)d_in[4];
    const float* ln1_b  = (const float*)d_in[5];
    const float* attn_w = (const float*)d_in[6];
    const float* attn_b = (const float*)d_in[7];
    const float* proj_w = (const float*)d_in[8];
    const float* proj_b = (const float*)d_in[9];
    const float* ln2_w  = (const float*)d_in[10];
    const float* ln2_b  = (const float*)d_in[11];
    const float* fc_w   = (const float*)d_in[12];
    const float* fc_b   = (const float*)d_in[13];
    const float* fc2_w  = (const float*)d_in[14];
    const float* fc2_b  = (const float*)d_in[15];
    const float* lnf_w  = (const float*)d_in[16];
    const float* lnf_b  = (const float*)d_in[17];
    float* out = (float*)d_out;

    char* p = (char*)d_ws;
    auto alloc = [&](size_t bytes) { char* q = p; p += (bytes + 255) & ~(size_t)255; return q; };
    float* x     = (float*)alloc((size_t)BT * DM * 4);
    float* nll   = (float*)alloc((size_t)BT * 4);
    bf16*  qkvb  = (bf16*) alloc((size_t)BT * 3 * DM * 2);
    bf16*  tmpb  = (bf16*) alloc((size_t)BT * DM * 2);
    bf16*  ctxb  = (bf16*) alloc((size_t)BT * DM * 2);
    bf16*  hb    = (bf16*) alloc((size_t)BT * 4 * DM * 2);
    bf16*  wteb  = (bf16*) alloc((size_t)VOCAB * DM * 2);
    bf16*  wqkvT = (bf16*) alloc((size_t)NLAYERS * 3 * DM * DM * 2);
    bf16*  wprojT= (bf16*) alloc((size_t)NLAYERS * DM * DM * 2);
    bf16*  wfcT  = (bf16*) alloc((size_t)NLAYERS * 4 * DM * DM * 2);
    bf16*  wfc2T = (bf16*) alloc((size_t)NLAYERS * 4 * DM * DM * 2);
    // loss partials (25.8 MB) alias the ctxb+hb region (31.5 MB, dead after layer loop)
    float2* partials = (float2*)ctxb;

    dim3 tb(32, 8);
    transpose_bf16_kernel<<<dim3(3 * DM / 32, DM / 32, NLAYERS), tb, 0, stream>>>(attn_w, wqkvT, DM, 3 * DM);
    transpose_bf16_kernel<<<dim3(DM / 32, DM / 32, NLAYERS), tb, 0, stream>>>(proj_w, wprojT, DM, DM);
    transpose_bf16_kernel<<<dim3(4 * DM / 32, DM / 32, NLAYERS), tb, 0, stream>>>(fc_w, wfcT, DM, 4 * DM);
    transpose_bf16_kernel<<<dim3(DM / 32, 4 * DM / 32, NLAYERS), tb, 0, stream>>>(fc2_w, wfc2T, 4 * DM, DM);
    {
        size_t n = (size_t)VOCAB * DM;
        tobf16_kernel<<<(unsigned)((n + 255) / 256), 256, 0, stream>>>(wte, wteb, n);
    }

    embed_kernel<<<BT * DM / 4 / 256, 256, 0, stream>>>(inp, wte, wpe, x);

    for (int i = 0; i < NLAYERS; ++i) {
        ln_kernel<<<BT, 256, 0, stream>>>(x, ln1_w + i * DM, ln1_b + i * DM, tmpb);
        gemm_bf16_kernel<<<dim3(BT / 128, 3 * DM / 128), 256, 0, stream>>>(
            tmpb, wqkvT + (size_t)i * 3 * DM * DM, attn_b + i * 3 * DM, nullptr,
            qkvb, nullptr, BT, 3 * DM, DM, GF_OBF16);
        flash_attn_kernel<<<dim3(TSEQ / 64, 4 * NHEADS), 256, 0, stream>>>(qkvb, ctxb);
        gemm_bf16_kernel<<<dim3(BT / 128, DM / 128), 256, 0, stream>>>(
            ctxb, wprojT + (size_t)i * DM * DM, proj_b + i * DM, x,
            x, nullptr, BT, DM, DM, 0);
        ln_kernel<<<BT, 256, 0, stream>>>(x, ln2_w + i * DM, ln2_b + i * DM, tmpb);
        gemm_bf16_kernel<<<dim3(BT / 128, 4 * DM / 128), 256, 0, stream>>>(
            tmpb, wfcT + (size_t)i * 4 * DM * DM, fc_b + i * 4 * DM, nullptr,
            hb, nullptr, BT, 4 * DM, DM, GF_GELU | GF_OBF16);
        gemm_bf16_kernel<<<dim3(BT / 128, DM / 128), 256, 0, stream>>>(
            hb, wfc2T + (size_t)i * 4 * DM * DM, fc2_b + i * DM, x,
            x, nullptr, BT, DM, 4 * DM, 0);
    }

    ln_kernel<<<BT, 256, 0, stream>>>(x, lnf_w, lnf_b, tmpb);
    gemm_bf16_kernel<<<dim3(BT / 128, (VOCAB + 127) / 128), 256, 0, stream>>>(
        tmpb, wteb, nullptr, nullptr, out, partials, BT, VOCAB, DM, GF_CLAMP | GF_PARTIAL);
    loss_reduce_kernel<<<BT, 256, 0, stream>>>(partials, out, target, nll);
    loss2_kernel<<<1, 1024, 0, stream>>>(nll, out + (size_t)out_size - 1);
}

// Round 6
// 4410.848 us; speedup vs baseline: 6.3979x; 1.0658x over previous
//
#include <hip/hip_runtime.h>
#include <hip/hip_bf16.h>
#include <cmath>

#define NLAYERS 12
#define NHEADS  12
#define DM      768
#define VOCAB   50257
#define TSEQ    1024
#define BT      4096   // B*T
#define NCHUNK  786    // ceil(VOCAB/64) col-chunks for loss partials

typedef __attribute__((ext_vector_type(4))) float f32x4;
typedef __attribute__((ext_vector_type(8))) short bf16x8;

typedef __hip_bfloat16 bf16;

#define MFMA16(a, b, c) __builtin_amdgcn_mfma_f32_16x16x32_bf16(a, b, c, 0, 0, 0)

// ---------------- helpers ----------------
__device__ __forceinline__ void gload16(const void* g, void* l) {
    __builtin_amdgcn_global_load_lds(
        (const __attribute__((address_space(1))) void*)g,
        (__attribute__((address_space(3))) void*)l, 16, 0, 0);
}

__device__ __forceinline__ float gelu_tanh(float v) {
    float u = 0.7978845608028654f * (v + 0.044715f * v * v * v);
    return 0.5f * v * (1.0f + tanhf(u));
}

__device__ __forceinline__ short f2bf(float f) {
    bf16 h = (bf16)f;
    return *reinterpret_cast<short*>(&h);
}

struct ushort4s { short a, b, c, d; };

// ---------------- weight prep ----------------
__global__ void transpose_bf16_kernel(const float* __restrict__ in, bf16* __restrict__ out,
                                      int K, int N) {
    __shared__ float tile[32][33];
    size_t lofs = (size_t)blockIdx.z * K * N;
    int k0 = blockIdx.y * 32, n0 = blockIdx.x * 32;
    int tx = threadIdx.x, ty = threadIdx.y;      // 32x8
#pragma unroll
    for (int i = 0; i < 32; i += 8)
        tile[ty + i][tx] = in[lofs + (size_t)(k0 + ty + i) * N + n0 + tx];
    __syncthreads();
#pragma unroll
    for (int i = 0; i < 32; i += 8)
        out[lofs + (size_t)(n0 + ty + i) * K + k0 + tx] = (bf16)tile[tx][ty + i];
}

__global__ void tobf16_kernel(const float* __restrict__ in, bf16* __restrict__ out, size_t n) {
    size_t i = (size_t)blockIdx.x * 256 + threadIdx.x;
    if (i < n) out[i] = (bf16)in[i];
}

// ---------------- embedding (fp32 residual stream, float4) ----------------
__global__ void embed_kernel(const int* __restrict__ inp, const float* __restrict__ wte,
                             const float* __restrict__ wpe, float* __restrict__ x) {
    int idx = blockIdx.x * 256 + threadIdx.x;    // over BT*DM/4
    int m = idx / (DM / 4), c4 = idx % (DM / 4);
    int tok = inp[m];
    int t = m & (TSEQ - 1);
    float4 a = reinterpret_cast<const float4*>(wte)[(size_t)tok * (DM / 4) + c4];
    float4 b = reinterpret_cast<const float4*>(wpe)[(size_t)t * (DM / 4) + c4];
    float4 o = {a.x + b.x, a.y + b.y, a.z + b.z, a.w + b.w};
    reinterpret_cast<float4*>(x)[idx] = o;
}

// ---------------- layernorm: fp32 in -> bf16 out (vectorized) ----------------
__global__ __launch_bounds__(256) void ln_kernel(const float* __restrict__ x,
                                                 const float* __restrict__ w,
                                                 const float* __restrict__ b,
                                                 bf16* __restrict__ y) {
    int row = blockIdx.x, tid = threadIdx.x;     // 256 threads, 192 active for data
    const float4* xr = reinterpret_cast<const float4*>(x + (size_t)row * DM);
    float4 v = {0.f, 0.f, 0.f, 0.f};
    float s = 0.f, q = 0.f;
    if (tid < 192) {
        v = xr[tid];
        s = v.x + v.y + v.z + v.w;
        q = v.x * v.x + v.y * v.y + v.z * v.z + v.w * v.w;
    }
#pragma unroll
    for (int o = 1; o < 64; o <<= 1) { s += __shfl_xor(s, o); q += __shfl_xor(q, o); }
    __shared__ float ss[4], qq[4];
    if ((tid & 63) == 0) { ss[tid >> 6] = s; qq[tid >> 6] = q; }
    __syncthreads();
    s = ss[0] + ss[1] + ss[2] + ss[3];
    q = qq[0] + qq[1] + qq[2] + qq[3];
    float mu  = s * (1.0f / DM);
    float var = q * (1.0f / DM) - mu * mu;
    float inv = rsqrtf(var + 1e-5f);
    if (tid < 192) {
        float4 wv = reinterpret_cast<const float4*>(w)[tid];
        float4 bv = reinterpret_cast<const float4*>(b)[tid];
        ushort4s o;
        o.a = f2bf((v.x - mu) * inv * wv.x + bv.x);
        o.b = f2bf((v.y - mu) * inv * wv.y + bv.y);
        o.c = f2bf((v.z - mu) * inv * wv.z + bv.z);
        o.d = f2bf((v.w - mu) * inv * wv.w + bv.w);
        *reinterpret_cast<ushort4s*>(y + (size_t)row * DM + tid * 4) = o;
    }
}

// ---------------- bf16 MFMA GEMM (2-phase double-buffered, T3 minimum recipe) ----------------
// C[M,N] = A[M,K] @ Bt[N,K]^T, fp32 accum. 128x128 tile, BK=32, 4 waves.
// One barrier (with implicit vmcnt+lgkm drain) per K-step; next tile's
// global_load_lds issued before current tile's ds_read+MFMA.
#define GF_GELU    1
#define GF_OBF16   2
#define GF_CLAMP   4
#define GF_PARTIAL 8   // emit per-(row, 64-col-chunk) (max, sumexp) partials for loss
#define GF_SWZ     16  // 1D grid + bijective XCD swizzle (nwg % 8 == 0), M-fast within chunk

template<int FLAGS, int TAG>
__global__ __launch_bounds__(256) void gemm_k(
    const bf16* __restrict__ A, const bf16* __restrict__ Bt,
    const float* __restrict__ bias, const float* __restrict__ resid,
    void* __restrict__ C, float2* __restrict__ partials,
    int M, int N, int K) {
    __shared__ short ldsA[2][128 * 32];
    __shared__ short ldsB[2][128 * 32];
    int tid = threadIdx.x;
    int lane = tid & 63, w = tid >> 6;
    int wm = w >> 1, wn = w & 1;
    int r = lane & 15, kq = lane >> 4;

    int bm, bn;
    if (FLAGS & GF_SWZ) {
        int bid = blockIdx.x;
        int q = gridDim.x >> 3;                  // nwg % 8 == 0 guaranteed by launcher
        int swz = (bid & 7) * q + (bid >> 3);    // XCD-contiguous chunks
        int mblocks = M >> 7;
        bm = (swz % mblocks) * 128;
        bn = (swz / mblocks) * 128;
    } else {
        bm = blockIdx.x * 128;
        bn = blockIdx.y * 128;
    }

    f32x4 acc[4][4] = {};

    auto stage = [&](int buf, int k0) {
#pragma unroll
        for (int i = 0; i < 2; ++i) {
            int chunk = i * 256 + tid;           // 16B chunk id = row*4 + dest granule
            int row = chunk >> 2;
            int gs = (chunk & 3) ^ ((row >> 1) & 3);   // swizzled source granule
            const bf16* ga = A + (size_t)(bm + row) * K + k0 + gs * 8;
            gload16(ga, &ldsA[buf][(i * 256 + w * 64) * 8]);
            int brow = bn + row;
            if (FLAGS & GF_CLAMP) brow = min(brow, N - 1);
            const bf16* gb = Bt + (size_t)brow * K + k0 + gs * 8;
            gload16(gb, &ldsB[buf][(i * 256 + w * 64) * 8]);
        }
    };
    auto compute = [&](int buf) {
        bf16x8 af[4], bfr[4];
#pragma unroll
        for (int m = 0; m < 4; ++m) {
            int row = wm * 64 + m * 16 + r;
            af[m] = *reinterpret_cast<bf16x8*>(&ldsA[buf][row * 32 + (kq ^ ((row >> 1) & 3)) * 8]);
        }
#pragma unroll
        for (int n = 0; n < 4; ++n) {
            int row = wn * 64 + n * 16 + r;
            bfr[n] = *reinterpret_cast<bf16x8*>(&ldsB[buf][row * 32 + (kq ^ ((row >> 1) & 3)) * 8]);
        }
#pragma unroll
        for (int m = 0; m < 4; ++m)
#pragma unroll
            for (int n = 0; n < 4; ++n)
                acc[m][n] = MFMA16(af[m], bfr[n], acc[m][n]);
    };

    stage(0, 0);
    __syncthreads();                             // drains vmcnt; buf0 ready
    int buf = 0;
    for (int k0 = 32; k0 < K; k0 += 32) {
        stage(buf ^ 1, k0);                      // prefetch flies under compute
        compute(buf);
        __syncthreads();                         // drain loads + reads, swap
        buf ^= 1;
    }
    compute(buf);

    int row0 = bm + wm * 64, col0 = bn + wn * 64;
#pragma unroll
    for (int m = 0; m < 4; ++m) {
#pragma unroll
        for (int n = 0; n < 4; ++n) {
            int col = col0 + n * 16 + r;
            if (col < N) {
#pragma unroll
                for (int rr = 0; rr < 4; ++rr) {
                    int row = row0 + m * 16 + kq * 4 + rr;
                    float v = acc[m][n][rr];
                    if (bias) v += bias[col];
                    if (FLAGS & GF_GELU) v = gelu_tanh(v);
                    if (resid) v += resid[(size_t)row * N + col];
                    if (FLAGS & GF_OBF16) ((bf16*)C)[(size_t)row * N + col] = (bf16)v;
                    else                  ((float*)C)[(size_t)row * N + col] = v;
                }
            }
        }
    }

    if (FLAGS & GF_PARTIAL) {
        int chunk = (bn >> 6) + wn;              // 64-col chunk index
#pragma unroll
        for (int m = 0; m < 4; ++m) {
#pragma unroll
            for (int rr = 0; rr < 4; ++rr) {
                float vals[4], mx = -INFINITY;
#pragma unroll
                for (int n = 0; n < 4; ++n) {
                    int col = col0 + n * 16 + r;
                    float v = (col < N) ? acc[m][n][rr] : -INFINITY;
                    vals[n] = v;
                    mx = fmaxf(mx, v);
                }
#pragma unroll
                for (int o = 1; o < 16; o <<= 1) mx = fmaxf(mx, __shfl_xor(mx, o));
                float sum = 0.f;
#pragma unroll
                for (int n = 0; n < 4; ++n)
                    if (vals[n] > -INFINITY) sum += __expf(vals[n] - mx);
#pragma unroll
                for (int o = 1; o < 16; o <<= 1) sum += __shfl_xor(sum, o);
                if (r == 0) {
                    int row = row0 + m * 16 + kq * 4 + rr;
                    partials[(size_t)row * NCHUNK + chunk] = make_float2(mx, sum);
                }
            }
        }
    }
}

// ---------------- flash attention (bf16 MFMA, online softmax) ----------------
// QBLK=64 (4 waves x 16 q-rows), KVBLK=128 (two 64-tiles per barrier round).
__global__ __launch_bounds__(256) void flash_attn_kernel(const bf16* __restrict__ qkv,
                                                         bf16* __restrict__ ctx) {
    __shared__ short Ks[128 * 64];       // K tile, 16B-chunk XOR-swizzled
    __shared__ short Vt[64][132];        // V^T tile  [d][kv], padded stride
    __shared__ short Ps[4][16][132];     // per-wave P tile [qrow][kv], padded stride

    int tid = threadIdx.x, lane = tid & 63, w = tid >> 6;
    int r = lane & 15, kq = lane >> 4;
    int q0 = blockIdx.x * 64;
    int bh = blockIdx.y;
    int b = bh / NHEADS, h = bh % NHEADS;
    const int RS = 3 * DM;               // qkv row stride

    const bf16* qbase = qkv + (size_t)(b * TSEQ + q0 + w * 16 + r) * RS + h * 64;
    bf16x8 qf[2];
    qf[0] = *reinterpret_cast<const bf16x8*>(qbase + kq * 8);
    qf[1] = *reinterpret_cast<const bf16x8*>(qbase + 32 + kq * 8);

    f32x4 of[4] = {};
    float mrow[4] = {-INFINITY, -INFINITY, -INFINITY, -INFINITY};
    float lrow[4] = {};

    int ntiles = (blockIdx.x >> 1) + 1;
    for (int t = 0; t < ntiles; ++t) {
        int kv0 = t * 128;
        __syncthreads();
        const bf16* kbase = qkv + (size_t)(b * TSEQ + kv0) * RS + DM + h * 64;
#pragma unroll
        for (int i = 0; i < 4; ++i) {
            int chunk = i * 256 + tid;
            int row = chunk >> 3, cp = chunk & 7;
            int csrc = cp ^ (row & 7);
            gload16(kbase + (size_t)row * RS + csrc * 8, Ks + chunk * 8);
        }
        const bf16* vbase = qkv + (size_t)(b * TSEQ + kv0) * RS + 2 * DM + h * 64;
#pragma unroll
        for (int i = 0; i < 4; ++i) {
            int chunk = i * 256 + tid;
            int kv = chunk >> 3, d0 = (chunk & 7) * 8;
            bf16x8 v = *reinterpret_cast<const bf16x8*>(vbase + (size_t)kv * RS + d0);
#pragma unroll
            for (int j = 0; j < 8; ++j) Vt[d0 + j][kv] = ((short*)&v)[j];
        }
        __syncthreads();

        f32x4 sf[8];
#pragma unroll
        for (int n = 0; n < 8; ++n) sf[n] = (f32x4){0.f, 0.f, 0.f, 0.f};
        __builtin_amdgcn_s_setprio(1);
#pragma unroll
        for (int n = 0; n < 8; ++n) {
            int row = n * 16 + r;
#pragma unroll
            for (int kt = 0; kt < 2; ++kt) {
                int gran = (kt * 4 + kq) ^ (row & 7);
                bf16x8 kf = *reinterpret_cast<bf16x8*>(&Ks[row * 64 + gran * 8]);
                sf[n] = MFMA16(qf[kt], kf, sf[n]);
            }
        }
        __builtin_amdgcn_s_setprio(0);

        bool diag = (kv0 + 128 > q0);
        float alpha[4];
#pragma unroll
        for (int rr = 0; rr < 4; ++rr) {
            int qrow = q0 + w * 16 + kq * 4 + rr;
            float vals[8];
            float mx = mrow[rr];
#pragma unroll
            for (int n = 0; n < 8; ++n) {
                float v = sf[n][rr] * 0.125f;
                if (diag && (kv0 + n * 16 + r) > qrow) v = -INFINITY;
                vals[n] = v;
                mx = fmaxf(mx, v);
            }
#pragma unroll
            for (int o = 1; o < 16; o <<= 1) mx = fmaxf(mx, __shfl_xor(mx, o));
            float al = __expf(mrow[rr] - mx);
            float sum = 0.f;
#pragma unroll
            for (int n = 0; n < 8; ++n) {
                float p = __expf(vals[n] - mx);
                vals[n] = p;
                sum += p;
            }
#pragma unroll
            for (int o = 1; o < 16; o <<= 1) sum += __shfl_xor(sum, o);
            mrow[rr] = mx;
            lrow[rr] = lrow[rr] * al + sum;
            alpha[rr] = al;
#pragma unroll
            for (int n = 0; n < 8; ++n) Ps[w][kq * 4 + rr][n * 16 + r] = f2bf(vals[n]);
        }
#pragma unroll
        for (int n = 0; n < 4; ++n)
#pragma unroll
            for (int rr = 0; rr < 4; ++rr) of[n][rr] *= alpha[rr];

        __builtin_amdgcn_s_setprio(1);
#pragma unroll
        for (int kt = 0; kt < 4; ++kt) {
            bf16x8 pa = *reinterpret_cast<bf16x8*>(&Ps[w][r][kt * 32 + kq * 8]);
#pragma unroll
            for (int n = 0; n < 4; ++n) {
                bf16x8 vf = *reinterpret_cast<bf16x8*>(&Vt[n * 16 + r][kt * 32 + kq * 8]);
                of[n] = MFMA16(pa, vf, of[n]);
            }
        }
        __builtin_amdgcn_s_setprio(0);
    }

#pragma unroll
    for (int rr = 0; rr < 4; ++rr) {
        float inv = 1.0f / lrow[rr];
        int qrow = q0 + w * 16 + kq * 4 + rr;
        bf16* cb = ctx + (size_t)(b * TSEQ + qrow) * DM + h * 64;
#pragma unroll
        for (int n = 0; n < 4; ++n) cb[n * 16 + r] = (bf16)(of[n][rr] * inv);
    }
}

// ---------------- loss: merge per-chunk partials ----------------
__global__ __launch_bounds__(256) void loss_reduce_kernel(const float2* __restrict__ partials,
                                                          const float* __restrict__ logits,
                                                          const int* __restrict__ target,
                                                          float* __restrict__ nll) {
    int row = blockIdx.x, tid = threadIdx.x;
    const float2* pr = partials + (size_t)row * NCHUNK;
    float m = -INFINITY, s = 0.f;
    for (int c = tid; c < NCHUNK; c += 256) {
        float2 p = pr[c];
        if (p.x > m) { s = s * __expf(m - p.x) + p.y; m = p.x; }
        else         { s += p.y * __expf(p.x - m); }
    }
    __shared__ float sm[256], ssum[256];
    sm[tid] = m; ssum[tid] = s; __syncthreads();
    for (int o = 128; o; o >>= 1) {
        if (tid < o) {
            float m2 = sm[tid + o], s2 = ssum[tid + o];
            float mm = fmaxf(sm[tid], m2);
            ssum[tid] = ssum[tid] * __expf(sm[tid] - mm) + s2 * __expf(m2 - mm);
            sm[tid] = mm;
        }
        __syncthreads();
    }
    if (tid == 0) {
        float lse = sm[0] + logf(ssum[0]);
        nll[row] = lse - logits[(size_t)row * VOCAB + target[row]];
    }
}

__global__ void loss2_kernel(const float* __restrict__ nll, float* __restrict__ loss) {
    int tid = threadIdx.x;
    float s = 0.f;
    for (int i = tid; i < BT; i += 1024) s += nll[i];
    __shared__ float r[1024];
    r[tid] = s; __syncthreads();
    for (int o = 512; o; o >>= 1) { if (tid < o) r[tid] += r[tid + o]; __syncthreads(); }
    if (tid == 0) *loss = r[0] * (1.0f / BT);
}

// ---------------- launcher ----------------
extern "C" void kernel_launch(void* const* d_in, const int* in_sizes, int n_in,
                              void* d_out, int out_size, void* d_ws, size_t ws_size,
                              hipStream_t stream) {
    const int*   inp    = (const int*)  d_in[0];
    const int*   target = (const int*)  d_in[1];
    const float* wte    = (const float*)d_in[2];
    const float* wpe    = (const float*)d_in[3];
    const float* ln1_w  = (const float*)d_in[4];
    const float* ln1_b  = (const float*)d_in[5];
    const float* attn_w = (const float*)d_in[6];
    const float* attn_b = (const float*)d_in[7];
    const float* proj_w = (const float*)d_in[8];
    const float* proj_b = (const float*)d_in[9];
    const float* ln2_w  = (const float*)d_in[10];
    const float* ln2_b  = (const float*)d_in[11];
    const float* fc_w   = (const float*)d_in[12];
    const float* fc_b   = (const float*)d_in[13];
    const float* fc2_w  = (const float*)d_in[14];
    const float* fc2_b  = (const float*)d_in[15];
    const float* lnf_w  = (const float*)d_in[16];
    const float* lnf_b  = (const float*)d_in[17];
    float* out = (float*)d_out;

    char* p = (char*)d_ws;
    auto alloc = [&](size_t bytes) { char* q = p; p += (bytes + 255) & ~(size_t)255; return q; };
    float* x     = (float*)alloc((size_t)BT * DM * 4);
    float* nll   = (float*)alloc((size_t)BT * 4);
    bf16*  qkvb  = (bf16*) alloc((size_t)BT * 3 * DM * 2);
    bf16*  tmpb  = (bf16*) alloc((size_t)BT * DM * 2);
    bf16*  ctxb  = (bf16*) alloc((size_t)BT * DM * 2);
    bf16*  hb    = (bf16*) alloc((size_t)BT * 4 * DM * 2);
    bf16*  wteb  = (bf16*) alloc((size_t)VOCAB * DM * 2);
    bf16*  wqkvT = (bf16*) alloc((size_t)NLAYERS * 3 * DM * DM * 2);
    bf16*  wprojT= (bf16*) alloc((size_t)NLAYERS * DM * DM * 2);
    bf16*  wfcT  = (bf16*) alloc((size_t)NLAYERS * 4 * DM * DM * 2);
    bf16*  wfc2T = (bf16*) alloc((size_t)NLAYERS * 4 * DM * DM * 2);
    // loss partials (25.8 MB) alias the ctxb+hb region (31.5 MB, dead after layer loop)
    float2* partials = (float2*)ctxb;

    dim3 tb(32, 8);
    transpose_bf16_kernel<<<dim3(3 * DM / 32, DM / 32, NLAYERS), tb, 0, stream>>>(attn_w, wqkvT, DM, 3 * DM);
    transpose_bf16_kernel<<<dim3(DM / 32, DM / 32, NLAYERS), tb, 0, stream>>>(proj_w, wprojT, DM, DM);
    transpose_bf16_kernel<<<dim3(4 * DM / 32, DM / 32, NLAYERS), tb, 0, stream>>>(fc_w, wfcT, DM, 4 * DM);
    transpose_bf16_kernel<<<dim3(DM / 32, 4 * DM / 32, NLAYERS), tb, 0, stream>>>(fc2_w, wfc2T, 4 * DM, DM);
    {
        size_t n = (size_t)VOCAB * DM;
        tobf16_kernel<<<(unsigned)((n + 255) / 256), 256, 0, stream>>>(wte, wteb, n);
    }

    embed_kernel<<<BT * DM / 4 / 256, 256, 0, stream>>>(inp, wte, wpe, x);

    for (int i = 0; i < NLAYERS; ++i) {
        ln_kernel<<<BT, 256, 0, stream>>>(x, ln1_w + i * DM, ln1_b + i * DM, tmpb);
        gemm_k<GF_OBF16, 0><<<dim3(BT / 128, 3 * DM / 128), 256, 0, stream>>>(
            tmpb, wqkvT + (size_t)i * 3 * DM * DM, attn_b + i * 3 * DM, nullptr,
            qkvb, nullptr, BT, 3 * DM, DM);
        flash_attn_kernel<<<dim3(TSEQ / 64, 4 * NHEADS), 256, 0, stream>>>(qkvb, ctxb);
        gemm_k<0, 1><<<dim3(BT / 128, DM / 128), 256, 0, stream>>>(
            ctxb, wprojT + (size_t)i * DM * DM, proj_b + i * DM, x,
            x, nullptr, BT, DM, DM);
        ln_kernel<<<BT, 256, 0, stream>>>(x, ln2_w + i * DM, ln2_b + i * DM, tmpb);
        gemm_k<GF_GELU | GF_OBF16, 2><<<dim3(BT / 128, 4 * DM / 128), 256, 0, stream>>>(
            tmpb, wfcT + (size_t)i * 4 * DM * DM, fc_b + i * 4 * DM, nullptr,
            hb, nullptr, BT, 4 * DM, DM);
        gemm_k<0, 3><<<dim3(BT / 128, DM / 128), 256, 0, stream>>>(
            hb, wfc2T + (size_t)i * 4 * DM * DM, fc2_b + i * DM, x,
            x, nullptr, BT, DM, 4 * DM);
    }

    ln_kernel<<<BT, 256, 0, stream>>>(x, lnf_w, lnf_b, tmpb);
    {
        int nwg = (BT / 128) * ((VOCAB + 127) / 128);   // 32 * 393 = 12576, % 8 == 0
        gemm_k<GF_CLAMP | GF_PARTIAL | GF_SWZ, 4><<<nwg, 256, 0, stream>>>(
            tmpb, wteb, nullptr, nullptr, out, partials, BT, VOCAB, DM);
    }
    loss_reduce_kernel<<<BT, 256, 0, stream>>>(partials, out, target, nll);
    loss2_kernel<<<1, 1024, 0, stream>>>(nll, out + (size_t)out_size - 1);
}